// Round 3
// baseline (1829.514 us; speedup 1.0000x reference)
//
#include <hip/hip_runtime.h>

#define NN 50000
#define NE 800000
#define NG 128
#define DIN 1280
#define HIDDEN 256
#define BNS 0.9999950000374997f
#define ATT_SCALE 0.027950849718747373f
#define LN_EPS 1e-5f

typedef __attribute__((ext_vector_type(8))) short short8;
typedef __attribute__((ext_vector_type(4))) float floatx4;

__device__ __forceinline__ float b2f(unsigned short u) {
  return __uint_as_float(((unsigned int)u) << 16);
}
__device__ __forceinline__ unsigned short f2b(float f) {
  unsigned int x = __float_as_uint(f);
  x += 0x7fffu + ((x >> 16) & 1u);
  return (unsigned short)(x >> 16);
}

// ---------------- weight prep ----------------
__global__ void transpose_w_k(const float* __restrict__ src, unsigned short* __restrict__ dst,
                              int K, int Nc) {
  int idx = blockIdx.x * 256 + threadIdx.x;
  if (idx >= K * Nc) return;
  int n = idx / K, k = idx % K;
  dst[idx] = f2b(src[(size_t)k * Nc + n]);
}

// M_h = qw_h @ kw_h^T; dst rows [0,1024)
__global__ void mw_k(const float* __restrict__ qw, const float* __restrict__ kw,
                     unsigned short* __restrict__ dst) {
  int col = blockIdx.x;      // 0..1023
  int d = threadIdx.x;       // 0..255
  int hh = col >> 8, dp = col & 255;
  const float* qr = qw + ((size_t)hh * 256 + d) * 256;
  const float* kr = kw + ((size_t)hh * 256 + dp) * 256;
  float s = 0.f;
  for (int e = 0; e < 256; e += 4) {
    float4 a = *(const float4*)(qr + e);
    float4 b = *(const float4*)(kr + e);
    s += a.x * b.x + a.y * b.y + a.z * b.z + a.w * b.w;
  }
  dst[(size_t)col * 256 + d] = f2b(s);
}

// W2[h,d,c] = sum_e vw[h,d,e] * ctw[h*256+e, c];  Bt layout dst[c*1024 + h*256+d]
__global__ void w2_k(const float* __restrict__ vw, const float* __restrict__ ctw,
                     unsigned short* __restrict__ dst) {
  int b = blockIdx.x;        // k index: h*256+d
  int c = threadIdx.x;       // 0..255
  int hh = b >> 8, d = b & 255;
  const float* vr = vw + ((size_t)hh * 256 + d) * 256;
  float s = 0.f;
  for (int e = 0; e < 256; ++e)
    s += vr[e] * ctw[(size_t)(hh * 256 + e) * 256 + c];
  dst[(size_t)c * 1024 + b] = f2b(s);
}

// ---------------- fused h->bf16 conversion + per-graph sum (float4) ----------------
__global__ void cvt_avg_k(const float* __restrict__ h, const int* __restrict__ gid,
                          unsigned short* __restrict__ h_bf, float* __restrict__ out1) {
  int row0 = blockIdx.x * 50;
  int tid = threadIdx.x;     // 0..319
  float4 acc = {0.f, 0.f, 0.f, 0.f};
  int cur_g = gid[row0];
  int c4 = tid * 4;
  for (int r = 0; r < 50; ++r) {
    int row = row0 + r;
    int g = gid[row];
    if (g != cur_g) {
      atomicAdd(&out1[(size_t)cur_g * DIN + c4 + 0], acc.x);
      atomicAdd(&out1[(size_t)cur_g * DIN + c4 + 1], acc.y);
      atomicAdd(&out1[(size_t)cur_g * DIN + c4 + 2], acc.z);
      atomicAdd(&out1[(size_t)cur_g * DIN + c4 + 3], acc.w);
      acc = {0.f, 0.f, 0.f, 0.f};
      cur_g = g;
    }
    float4 v = *(const float4*)(h + (size_t)row * DIN + c4);
    acc.x += v.x; acc.y += v.y; acc.z += v.z; acc.w += v.w;
    ushort4 o;
    o.x = f2b(v.x); o.y = f2b(v.y); o.z = f2b(v.z); o.w = f2b(v.w);
    *(ushort4*)(h_bf + (size_t)row * DIN + c4) = o;
  }
  atomicAdd(&out1[(size_t)cur_g * DIN + c4 + 0], acc.x);
  atomicAdd(&out1[(size_t)cur_g * DIN + c4 + 1], acc.y);
  atomicAdd(&out1[(size_t)cur_g * DIN + c4 + 2], acc.z);
  atomicAdd(&out1[(size_t)cur_g * DIN + c4 + 3], acc.w);
}

__global__ void div_avg_k(const int* __restrict__ start, float* __restrict__ out1) {
  int idx = blockIdx.x * 256 + threadIdx.x;
  if (idx >= NG * DIN) return;
  int g = idx / DIN;
  float cnt = (float)(start[g + 1] - start[g]);
  if (cnt < 1.f) cnt = 1.f;
  out1[idx] /= cnt;
}

// ---------------- graph structure ----------------
__global__ void graph_bounds_k(const int* __restrict__ gid, int* __restrict__ start, int n) {
  int i = blockIdx.x * 256 + threadIdx.x;
  if (i >= n) return;
  int g = gid[i];
  if (i == 0) {
    for (int gg = 0; gg <= g; ++gg) start[gg] = 0;
  } else {
    int gp = gid[i - 1];
    for (int gg = gp + 1; gg <= g; ++gg) start[gg] = i;
  }
  if (i == n - 1) {
    for (int gg = g + 1; gg <= NG; ++gg) start[gg] = n;
  }
}

__global__ void degrees_k(const int* __restrict__ src, const int* __restrict__ dst,
                          int* __restrict__ deg_out, int* __restrict__ deg_in, int e) {
  int i = blockIdx.x * 256 + threadIdx.x;
  if (i >= e) return;
  atomicAdd(&deg_out[src[i]], 1);
  atomicAdd(&deg_in[dst[i]], 1);
}

__global__ void invsqrt_k(const int* __restrict__ deg_out, const int* __restrict__ deg_in,
                          float* __restrict__ ns, float* __restrict__ nd, int n) {
  int i = blockIdx.x * 256 + threadIdx.x;
  if (i >= n) return;
  int a = deg_out[i]; if (a < 1) a = 1;
  int b = deg_in[i];  if (b < 1) b = 1;
  ns[i] = rsqrtf((float)a);
  nd[i] = rsqrtf((float)b);
}

// 3-kernel scan: local scans, block-sum scan, add offsets
__global__ void scan_local_k(const int* __restrict__ deg, int* __restrict__ row_ptr,
                             int* __restrict__ bsum) {
  __shared__ int buf[256];
  int b = blockIdx.x, t = threadIdx.x;
  int i = b * 256 + t;
  int v = (i < NN) ? deg[i] : 0;
  buf[t] = v;
  __syncthreads();
  for (int off = 1; off < 256; off <<= 1) {
    int tv = (t >= off) ? buf[t - off] : 0;
    __syncthreads();
    buf[t] += tv;
    __syncthreads();
  }
  if (i < NN) row_ptr[i] = buf[t] - v;
  if (t == 255) bsum[b] = buf[255];
}

__global__ void scan_bsum_k(int* __restrict__ bsum, int* __restrict__ boff, int nb,
                            int* __restrict__ row_ptr) {
  __shared__ int buf[256];
  int t = threadIdx.x;
  int v = (t < nb) ? bsum[t] : 0;
  buf[t] = v;
  __syncthreads();
  for (int off = 1; off < 256; off <<= 1) {
    int tv = (t >= off) ? buf[t - off] : 0;
    __syncthreads();
    buf[t] += tv;
    __syncthreads();
  }
  if (t < nb) boff[t] = buf[t] - v;
  if (t == 0) row_ptr[NN] = NE;
}

__global__ void scan_add_k(int* __restrict__ row_ptr, const int* __restrict__ boff) {
  int i = blockIdx.x * 256 + threadIdx.x;
  if (i >= NN) return;
  row_ptr[i] += boff[blockIdx.x];
}

__global__ void fill_csr_k(const int* __restrict__ src, const int* __restrict__ dst,
                           const int* __restrict__ row_ptr, int* __restrict__ fill,
                           int* __restrict__ csr_src, int e) {
  int i = blockIdx.x * 256 + threadIdx.x;
  if (i >= e) return;
  int d = dst[i];
  int pos = row_ptr[d] + atomicAdd(&fill[d], 1);
  csr_src[pos] = src[i];
}

// ---------------- bf16 MFMA GEMM ----------------
// C[M,Nc] = A[M,K] * Bt[Nc,K]   (both bf16)
// LDS layout: cell(r,kb) = r*8 + (kb ^ (r&7)); double-buffered (2x32KB).
// Pipeline: stage(t+1) issued BEFORE compute(t); single __syncthreads per
// k-step (its implicit vmcnt(0)+lgkmcnt(0) drain is covered by the MFMAs).
// MODE 0: bf16 out; 1: fp32 out; 2: +bias relu bf16 out;
// MODE 4: att epilogue (quadratic form row-dot with xtile), no C store
// MODE 6: A synthesized as xb[gm, k&255] * ascale[gm*4 + (k>>8)] (reg-staged, single-buffer)
// MODE 7: gate epilogue: xb = sigmoid(acc+bias)*xcat[:,c] + (1-s)*xcat[:,256+c]
// MODE 8: bf16 out + fused el/er epilogue for gat cols (>= ecol0).
//         If gridDim.z==2: z=0 -> (hg0,w1t,m1) no elr; z=1 -> shifted ptrs (ha0,w1gt,f1) + elr.
template <int MODE>
__global__ __launch_bounds__(256, 2) void gemm_bf16(const unsigned short* __restrict__ A,
                                                    const unsigned short* __restrict__ Bt,
                                                    void* __restrict__ Cout,
                                                    const float* __restrict__ bias,
                                                    int M, int K, int Nc,
                                                    const unsigned short* __restrict__ xtile,
                                                    float* __restrict__ attp,
                                                    const float* __restrict__ ascale,
                                                    const float* __restrict__ al,
                                                    const float* __restrict__ ar,
                                                    float* __restrict__ elr,
                                                    int ecol0) {
  __shared__ unsigned short sbuf[32768];
  const int tid = threadIdx.x;
  const int n0 = blockIdx.x * 128;
  const int m0 = blockIdx.y * 128;
  const int w = tid >> 6;
  const int lane = tid & 63;
  const int wr = (w >> 1) * 64;
  const int wc = (w & 1) * 64;
  const int quad = lane >> 4;
  const int l15 = lane & 15;
  const int js = tid & 7;
  const int mbase = tid >> 3;
  const int wbase = w * 64;

  bool do_elr = (MODE == 8);
  const unsigned short* Ap = A;
  const unsigned short* Bp = Bt;
  unsigned short* Cp = (unsigned short*)Cout;
  if (MODE == 8 && gridDim.z == 2) {
    if (blockIdx.z == 0) {
      do_elr = false;
    } else {
      Ap += 12800000;   // ha0 - hg0 (ushorts)
      Bp += 65536;      // w1gt - w1t
      Cp += 12800000;   // f1 - m1
    }
  }

  floatx4 acc[4][4];
#pragma unroll
  for (int i = 0; i < 4; ++i)
#pragma unroll
    for (int j = 0; j < 4; ++j) acc[i][j] = (floatx4)0.0f;

  if constexpr (MODE == 6) {
    // single-buffered reg-staged path (A synthesized from xb * alpha)
    unsigned short* lA = sbuf;
    unsigned short* lB = sbuf + 8192;
    for (int k0 = 0; k0 < K; k0 += 64) {
      __syncthreads();
#pragma unroll
      for (int it = 0; it < 4; ++it) {
        int m = it * 32 + mbase;
        int gm = m0 + m;
        if (gm >= M) gm = M - 1;
        uint4 va = *(const uint4*)(Ap + (size_t)gm * 256 + (k0 & 255) + js * 8);
        float s = ascale[(size_t)gm * 4 + (k0 >> 8)];
        unsigned short* pp = (unsigned short*)&va;
#pragma unroll
        for (int c = 0; c < 8; ++c) pp[c] = f2b(b2f(pp[c]) * s);
        *(uint4*)(lA + (size_t)(m * 8 + (js ^ (m & 7))) * 8) = va;
      }
#pragma unroll
      for (int it = 0; it < 4; ++it) {
        int c = it * 256 + wbase + lane;
        int m = c >> 3, g = c & 7;
        int gn = n0 + m;
        const unsigned short* gp = Bp + (size_t)gn * K + k0 + (g ^ (m & 7)) * 8;
        __builtin_amdgcn_global_load_lds(
            (const __attribute__((address_space(1))) unsigned int*)gp,
            (__attribute__((address_space(3))) unsigned int*)(lB + (size_t)(it * 256 + wbase) * 8),
            16, 0, 0);
      }
      __syncthreads();
#pragma unroll
      for (int ks = 0; ks < 2; ++ks) {
        int kb = ks * 4 + quad;
        short8 af[4], bfr[4];
#pragma unroll
        for (int ri = 0; ri < 4; ++ri) {
          int r = wr + ri * 16 + l15;
          af[ri] = *(const short8*)(lA + (size_t)(r * 8 + (kb ^ (r & 7))) * 8);
        }
#pragma unroll
        for (int ci = 0; ci < 4; ++ci) {
          int c = wc + ci * 16 + l15;
          bfr[ci] = *(const short8*)(lB + (size_t)(c * 8 + (kb ^ (c & 7))) * 8);
        }
#pragma unroll
        for (int ri = 0; ri < 4; ++ri)
#pragma unroll
          for (int ci = 0; ci < 4; ++ci)
            acc[ri][ci] = __builtin_amdgcn_mfma_f32_16x16x32_bf16(af[ri], bfr[ci], acc[ri][ci], 0, 0, 0);
      }
    }
    __syncthreads();
  } else {
    const int nt = K >> 6;
    auto stage = [&](int b, int k0) {
      unsigned short* lA = sbuf + b * 16384;
      unsigned short* lB = lA + 8192;
#pragma unroll
      for (int it = 0; it < 4; ++it) {
        int c = it * 256 + wbase + lane;
        int m = c >> 3, g = c & 7;
        int gm = m0 + m;
        if (gm >= M) gm = M - 1;
        const unsigned short* gp = Ap + (size_t)gm * K + k0 + (g ^ (m & 7)) * 8;
        __builtin_amdgcn_global_load_lds(
            (const __attribute__((address_space(1))) unsigned int*)gp,
            (__attribute__((address_space(3))) unsigned int*)(lA + (size_t)(it * 256 + wbase) * 8),
            16, 0, 0);
      }
#pragma unroll
      for (int it = 0; it < 4; ++it) {
        int c = it * 256 + wbase + lane;
        int m = c >> 3, g = c & 7;
        int gn = n0 + m;
        const unsigned short* gp = Bp + (size_t)gn * K + k0 + (g ^ (m & 7)) * 8;
        __builtin_amdgcn_global_load_lds(
            (const __attribute__((address_space(1))) unsigned int*)gp,
            (__attribute__((address_space(3))) unsigned int*)(lB + (size_t)(it * 256 + wbase) * 8),
            16, 0, 0);
      }
    };
    stage(0, 0);
    __syncthreads();
    for (int t = 0; t < nt; ++t) {
      int cur = t & 1;
      if (t + 1 < nt) stage(cur ^ 1, (t + 1) * 64);
      unsigned short* lA = sbuf + cur * 16384;
      unsigned short* lB = lA + 8192;
#pragma unroll
      for (int ks = 0; ks < 2; ++ks) {
        int kb = ks * 4 + quad;
        short8 af[4], bfr[4];
#pragma unroll
        for (int ri = 0; ri < 4; ++ri) {
          int r = wr + ri * 16 + l15;
          af[ri] = *(const short8*)(lA + (size_t)(r * 8 + (kb ^ (r & 7))) * 8);
        }
#pragma unroll
        for (int ci = 0; ci < 4; ++ci) {
          int c = wc + ci * 16 + l15;
          bfr[ci] = *(const short8*)(lB + (size_t)(c * 8 + (kb ^ (c & 7))) * 8);
        }
#pragma unroll
        for (int ri = 0; ri < 4; ++ri)
#pragma unroll
          for (int ci = 0; ci < 4; ++ci)
            acc[ri][ci] = __builtin_amdgcn_mfma_f32_16x16x32_bf16(af[ri], bfr[ci], acc[ri][ci], 0, 0, 0);
      }
      __syncthreads();
    }
  }

  if (MODE == 4) {
    // att epilogue: att[n,h] += sum_col acc * xb[n,col]; no C store
    int cb = n0 & 255;
#pragma unroll
    for (int it2 = 0; it2 < 8; ++it2) {
      int linear = it2 * 256 + tid;
      int rr = linear >> 4;
      int c8 = (linear & 15) * 8;
      int gr = m0 + rr;
      if (gr >= M) gr = M - 1;
      *(uint4*)(sbuf + rr * 128 + c8) = *(const uint4*)(xtile + (size_t)gr * 256 + cb + c8);
    }
    __syncthreads();
    int head = n0 >> 8;
#pragma unroll
    for (int ri = 0; ri < 4; ++ri) {
      int lrow = wr + ri * 16 + quad * 4;
#pragma unroll
      for (int r = 0; r < 4; ++r) {
        float p = 0.f;
#pragma unroll
        for (int ci = 0; ci < 4; ++ci)
          p += acc[ri][ci][r] * b2f(sbuf[(lrow + r) * 128 + wc + ci * 16 + l15]);
        p += __shfl_xor(p, 1);
        p += __shfl_xor(p, 2);
        p += __shfl_xor(p, 4);
        p += __shfl_xor(p, 8);
        if (l15 == 0) {
          int grow = m0 + lrow + r;
          if (grow < M) atomicAdd(&attp[(size_t)grow * 4 + head], p * ATT_SCALE);
        }
      }
    }
    return;
  }

  if (MODE == 7) {
    // gate epilogue: g = sigmoid(acc + bias[col]); out = g*xcat[:,col] + (1-g)*xcat[:,256+col]
#pragma unroll
    for (int ri = 0; ri < 4; ++ri) {
      int row = m0 + wr + ri * 16 + quad * 4;
#pragma unroll
      for (int ci = 0; ci < 4; ++ci) {
        int col = n0 + wc + ci * 16 + l15;
        float bv = bias[col];
#pragma unroll
        for (int r = 0; r < 4; ++r) {
          if (row + r < M) {
            float g = 1.f / (1.f + expf(-(acc[ri][ci][r] + bv)));
            float hg = b2f(xtile[(size_t)(row + r) * 512 + col]);
            float ha = b2f(xtile[(size_t)(row + r) * 512 + 256 + col]);
            Cp[(size_t)(row + r) * Nc + col] = f2b(g * hg + (1.f - g) * ha);
          }
        }
      }
    }
    return;
  }

  if (MODE == 8 && do_elr && n0 >= ecol0) {
    // fused el/er: this wave's 64 cols are exactly one head's 64 dims
    int head = (n0 - ecol0 + wc) >> 6;
#pragma unroll
    for (int ri = 0; ri < 4; ++ri) {
      int lrow = wr + ri * 16 + quad * 4;
#pragma unroll
      for (int r = 0; r < 4; ++r) {
        float pl = 0.f, pr = 0.f;
#pragma unroll
        for (int ci = 0; ci < 4; ++ci) {
          float fv = acc[ri][ci][r];
          pl += fv * al[head * 64 + ci * 16 + l15];
          pr += fv * ar[head * 64 + ci * 16 + l15];
        }
        pl += __shfl_xor(pl, 1); pl += __shfl_xor(pl, 2);
        pl += __shfl_xor(pl, 4); pl += __shfl_xor(pl, 8);
        pr += __shfl_xor(pr, 1); pr += __shfl_xor(pr, 2);
        pr += __shfl_xor(pr, 4); pr += __shfl_xor(pr, 8);
        if (l15 == 0) {
          int grow = m0 + lrow + r;
          if (grow < M) {
            elr[(size_t)grow * 8 + head] = pl;
            elr[(size_t)grow * 8 + 4 + head] = pr;
          }
        }
      }
    }
  }

#pragma unroll
  for (int ri = 0; ri < 4; ++ri) {
    int row = m0 + wr + ri * 16 + quad * 4;
#pragma unroll
    for (int ci = 0; ci < 4; ++ci) {
      int col = n0 + wc + ci * 16 + l15;
      float bv = (MODE == 2) ? bias[col] : 0.f;
#pragma unroll
      for (int r = 0; r < 4; ++r) {
        if (row + r < M) {
          float v = acc[ri][ci][r];
          if (MODE == 2) { v += bv; v = fmaxf(v, 0.f); }
          if (MODE == 1)
            ((float*)Cout)[(size_t)(row + r) * Nc + col] = v;
          else
            Cp[(size_t)(row + r) * Nc + col] = f2b(v);
        }
      }
    }
  }
}

// ---------------- GCN aggregation ----------------
__global__ void gcn_agg_k(const unsigned short* __restrict__ m, int ldm,
                          const int* __restrict__ row_ptr, const int* __restrict__ csr_src,
                          const float* __restrict__ ns, const float* __restrict__ nd,
                          const float* __restrict__ bias,
                          const float* __restrict__ bng, const float* __restrict__ bnb,
                          const unsigned short* __restrict__ resid, int ldr,
                          unsigned short* __restrict__ out, int ldo) {
  int node = blockIdx.x * 4 + (threadIdx.x >> 6);
  if (node >= NN) return;
  int lane = threadIdx.x & 63;
  int s = row_ptr[node], e = row_ptr[node + 1];
  float a0 = 0, a1 = 0, a2 = 0, a3 = 0;
  for (int i = s; i < e; ++i) {
    int u = csr_src[i];
    float w = ns[u];
    ushort4 v = *(const ushort4*)(m + (size_t)u * ldm + lane * 4);
    a0 += w * b2f(v.x); a1 += w * b2f(v.y); a2 += w * b2f(v.z); a3 += w * b2f(v.w);
  }
  float ndv = nd[node];
  int col = lane * 4;
  float vals[4] = {a0, a1, a2, a3};
  ushort4 o;
#pragma unroll
  for (int c = 0; c < 4; ++c) {
    float v = vals[c] * ndv + bias[col + c];
    v = bng[col + c] * v * BNS + bnb[col + c];
    v = fmaxf(v, 0.f);
    if (resid) v += b2f(resid[(size_t)node * ldr + col + c]);
    ((unsigned short*)&o)[c] = f2b(v);
  }
  *(ushort4*)(out + (size_t)node * ldo + col) = o;
}

// ---------------- GAT aggregation ----------------
__global__ void gat_agg_k(const unsigned short* __restrict__ f, int ldf,
                          const int* __restrict__ row_ptr, const int* __restrict__ csr_src,
                          const float* __restrict__ elr,
                          const float* __restrict__ bias,
                          const float* __restrict__ bng, const float* __restrict__ bnb,
                          const unsigned short* __restrict__ resid, int ldr,
                          unsigned short* __restrict__ out, int ldo) {
  int node = blockIdx.x * 4 + (threadIdx.x >> 6);
  if (node >= NN) return;
  int lane = threadIdx.x & 63;
  int s = row_ptr[node], e = row_ptr[node + 1];
  float4 er = *(const float4*)(elr + (size_t)node * 8 + 4);
  float m0 = -1e30f, m1 = -1e30f, m2 = -1e30f, m3 = -1e30f;
  for (int i = s + lane; i < e; i += 64) {
    int u = csr_src[i];
    float4 el = *(const float4*)(elr + (size_t)u * 8);
    float t;
    t = el.x + er.x; t = t > 0.f ? t : 0.2f * t; m0 = fmaxf(m0, t);
    t = el.y + er.y; t = t > 0.f ? t : 0.2f * t; m1 = fmaxf(m1, t);
    t = el.z + er.z; t = t > 0.f ? t : 0.2f * t; m2 = fmaxf(m2, t);
    t = el.w + er.w; t = t > 0.f ? t : 0.2f * t; m3 = fmaxf(m3, t);
  }
#pragma unroll
  for (int off = 1; off < 64; off <<= 1) {
    m0 = fmaxf(m0, __shfl_xor(m0, off));
    m1 = fmaxf(m1, __shfl_xor(m1, off));
    m2 = fmaxf(m2, __shfl_xor(m2, off));
    m3 = fmaxf(m3, __shfl_xor(m3, off));
  }
  float s0 = 0, s1 = 0, s2 = 0, s3 = 0;
  for (int i = s + lane; i < e; i += 64) {
    int u = csr_src[i];
    float4 el = *(const float4*)(elr + (size_t)u * 8);
    float t;
    t = el.x + er.x; t = t > 0.f ? t : 0.2f * t; s0 += expf(t - m0);
    t = el.y + er.y; t = t > 0.f ? t : 0.2f * t; s1 += expf(t - m1);
    t = el.z + er.z; t = t > 0.f ? t : 0.2f * t; s2 += expf(t - m2);
    t = el.w + er.w; t = t > 0.f ? t : 0.2f * t; s3 += expf(t - m3);
  }
#pragma unroll
  for (int off = 1; off < 64; off <<= 1) {
    s0 += __shfl_xor(s0, off);
    s1 += __shfl_xor(s1, off);
    s2 += __shfl_xor(s2, off);
    s3 += __shfl_xor(s3, off);
  }
  int head = lane >> 4;
  float erh = head == 0 ? er.x : head == 1 ? er.y : head == 2 ? er.z : er.w;
  float mh = head == 0 ? m0 : head == 1 ? m1 : head == 2 ? m2 : m3;
  float sh = head == 0 ? s0 : head == 1 ? s1 : head == 2 ? s2 : s3;
  float inv_sh = (sh > 0.f) ? 1.f / sh : 0.f;
  float a0 = 0, a1 = 0, a2 = 0, a3 = 0;
  for (int i = s; i < e; ++i) {
    int u = csr_src[i];
    float t = elr[(size_t)u * 8 + head] + erh;
    t = t > 0.f ? t : 0.2f * t;
    float wgt = expf(t - mh) * inv_sh;
    ushort4 v = *(const ushort4*)(f + (size_t)u * ldf + lane * 4);
    a0 += wgt * b2f(v.x); a1 += wgt * b2f(v.y); a2 += wgt * b2f(v.z); a3 += wgt * b2f(v.w);
  }
  int col = lane * 4;
  float vals[4] = {a0, a1, a2, a3};
  ushort4 o;
#pragma unroll
  for (int c = 0; c < 4; ++c) {
    float v = vals[c] + bias[col + c];
    v = bng[col + c] * v * BNS + bnb[col + c];
    v = (v > 0.f) ? v : (expf(v) - 1.f);
    if (resid) v += b2f(resid[(size_t)node * ldr + col + c]);
    ((unsigned short*)&o)[c] = f2b(v);
  }
  *(ushort4*)(out + (size_t)node * ldo + col) = o;
}

// ---------------- per-graph node softmax ----------------
__global__ void gsoftmax_k(const float* __restrict__ att, const int* __restrict__ start,
                           float* __restrict__ alpha) {
  int g = blockIdx.x;
  int s = start[g], e = start[g + 1];
  int tid = threadIdx.x;
  __shared__ float red[256];
  __shared__ float mh[4], sh[4];
  float lm[4] = {-1e30f, -1e30f, -1e30f, -1e30f};
  for (int i = s + tid; i < e; i += 256) {
    float4 a = *(const float4*)(att + (size_t)i * 4);
    lm[0] = fmaxf(lm[0], a.x); lm[1] = fmaxf(lm[1], a.y);
    lm[2] = fmaxf(lm[2], a.z); lm[3] = fmaxf(lm[3], a.w);
  }
#pragma unroll
  for (int h = 0; h < 4; ++h) {
    red[tid] = lm[h]; __syncthreads();
    for (int off = 128; off > 0; off >>= 1) {
      if (tid < off) red[tid] = fmaxf(red[tid], red[tid + off]);
      __syncthreads();
    }
    if (tid == 0) mh[h] = red[0];
    __syncthreads();
  }
  float ls[4] = {0, 0, 0, 0};
  for (int i = s + tid; i < e; i += 256) {
    float4 a = *(const float4*)(att + (size_t)i * 4);
    ls[0] += expf(a.x - mh[0]); ls[1] += expf(a.y - mh[1]);
    ls[2] += expf(a.z - mh[2]); ls[3] += expf(a.w - mh[3]);
  }
#pragma unroll
  for (int h = 0; h < 4; ++h) {
    red[tid] = ls[h]; __syncthreads();
    for (int off = 128; off > 0; off >>= 1) {
      if (tid < off) red[tid] += red[tid + off];
      __syncthreads();
    }
    if (tid == 0) sh[h] = red[0];
    __syncthreads();
  }
  for (int i = s + tid; i < e; i += 256) {
    float4 a = *(const float4*)(att + (size_t)i * 4);
    float4 o;
    o.x = expf(a.x - mh[0]) / sh[0];
    o.y = expf(a.y - mh[1]) / sh[1];
    o.z = expf(a.z - mh[2]) / sh[2];
    o.w = expf(a.w - mh[3]) / sh[3];
    *(float4*)(alpha + (size_t)i * 4) = o;
  }
}

// ---------------- LayerNorms (all bf16 in/out) ----------------
__global__ void ln1_k(const unsigned short* __restrict__ mo, const unsigned short* __restrict__ x,
                      const float* __restrict__ g, const float* __restrict__ b,
                      unsigned short* __restrict__ x1) {
  int node = blockIdx.x * 4 + (threadIdx.x >> 6);
  if (node >= NN) return;
  int lane = threadIdx.x & 63;
  int c = lane * 4;
  ushort4 a = *(const ushort4*)(mo + (size_t)node * HIDDEN + c);
  ushort4 xx = *(const ushort4*)(x + (size_t)node * HIDDEN + c);
  float v0 = b2f(a.x) + b2f(xx.x), v1 = b2f(a.y) + b2f(xx.y);
  float v2 = b2f(a.z) + b2f(xx.z), v3 = b2f(a.w) + b2f(xx.w);
  float sm = v0 + v1 + v2 + v3;
#pragma unroll
  for (int off = 1; off < 64; off <<= 1) sm += __shfl_xor(sm, off);
  float mu = sm * (1.f / 256.f);
  float d0 = v0 - mu, d1 = v1 - mu, d2 = v2 - mu, d3 = v3 - mu;
  float sq = d0 * d0 + d1 * d1 + d2 * d2 + d3 * d3;
#pragma unroll
  for (int off = 1; off < 64; off <<= 1) sq += __shfl_xor(sq, off);
  float inv = rsqrtf(sq * (1.f / 256.f) + LN_EPS);
  ushort4 ob;
  ob.x = f2b(g[c + 0] * d0 * inv + b[c + 0]);
  ob.y = f2b(g[c + 1] * d1 * inv + b[c + 1]);
  ob.z = f2b(g[c + 2] * d2 * inv + b[c + 2]);
  ob.w = f2b(g[c + 3] * d3 * inv + b[c + 3]);
  *(ushort4*)(x1 + (size_t)node * HIDDEN + c) = ob;
}

// ln2 with fused per-graph readout (atomicAdd into out0)
__global__ void ln2_k(const unsigned short* __restrict__ ff2o, const float* __restrict__ ffb2,
                      const unsigned short* __restrict__ x1,
                      const float* __restrict__ g, const float* __restrict__ b,
                      const int* __restrict__ gid, float* __restrict__ out0) {
  int node = blockIdx.x * 4 + (threadIdx.x >> 6);
  if (node >= NN) return;
  int lane = threadIdx.x & 63;
  int c = lane * 4;
  ushort4 a = *(const ushort4*)(ff2o + (size_t)node * HIDDEN + c);
  ushort4 xx = *(const ushort4*)(x1 + (size_t)node * HIDDEN + c);
  float v0 = b2f(a.x) + ffb2[c + 0] + b2f(xx.x), v1 = b2f(a.y) + ffb2[c + 1] + b2f(xx.y);
  float v2 = b2f(a.z) + ffb2[c + 2] + b2f(xx.z), v3 = b2f(a.w) + ffb2[c + 3] + b2f(xx.w);
  float sm = v0 + v1 + v2 + v3;
#pragma unroll
  for (int off = 1; off < 64; off <<= 1) sm += __shfl_xor(sm, off);
  float mu = sm * (1.f / 256.f);
  float d0 = v0 - mu, d1 = v1 - mu, d2 = v2 - mu, d3 = v3 - mu;
  float sq = d0 * d0 + d1 * d1 + d2 * d2 + d3 * d3;
#pragma unroll
  for (int off = 1; off < 64; off <<= 1) sq += __shfl_xor(sq, off);
  float inv = rsqrtf(sq * (1.f / 256.f) + LN_EPS);
  int gg = gid[node];
  float r0 = b2f(f2b(g[c + 0] * d0 * inv + b[c + 0]));
  float r1 = b2f(f2b(g[c + 1] * d1 * inv + b[c + 1]));
  float r2 = b2f(f2b(g[c + 2] * d2 * inv + b[c + 2]));
  float r3 = b2f(f2b(g[c + 3] * d3 * inv + b[c + 3]));
  atomicAdd(&out0[(size_t)gg * HIDDEN + c + 0], r0);
  atomicAdd(&out0[(size_t)gg * HIDDEN + c + 1], r1);
  atomicAdd(&out0[(size_t)gg * HIDDEN + c + 2], r2);
  atomicAdd(&out0[(size_t)gg * HIDDEN + c + 3], r3);
}

// ---------------- workspace layout (bytes) ----------------
static const size_t OFF_BUFA   = 0;
static const size_t OFF_C01    = 128000000;
static const size_t OFF_HG0    = 179200000;
static const size_t OFF_HA0    = 204800000;
static const size_t OFF_M1     = 230400000;
static const size_t OFF_F1     = 256000000;
static const size_t OFF_XCAT   = 281600000;
static const size_t OFF_GLOGIT = 332800000;
static const size_t OFF_XB     = 358400000;
static const size_t OFF_MO     = 384000000;
static const size_t OFF_X1     = 409600000;
static const size_t OFF_ATT    = 435200000;
static const size_t OFF_ALPHA  = OFF_ATT + 800000;
static const size_t OFF_ELR0   = OFF_ALPHA + 800000;
static const size_t OFF_ELR1   = OFF_ELR0 + 1600000;
static const size_t OFF_START  = OFF_ELR1 + 1600000;
static const size_t OFF_DEGO   = OFF_START + 1024;
static const size_t OFF_DEGI   = OFF_DEGO + 200704;
static const size_t OFF_NS     = OFF_DEGI + 200704;
static const size_t OFF_ND     = OFF_NS + 200704;
static const size_t OFF_ROWP   = OFF_ND + 200704;
static const size_t OFF_FILL   = OFF_ROWP + 200704;
static const size_t OFF_BSUM   = OFF_FILL + 200704;
static const size_t OFF_BOFF   = OFF_BSUM + 1024;
static const size_t OFF_CSRS   = OFF_BOFF + 1024;
static const size_t OFF_W01T   = OFF_CSRS + 3200000;
static const size_t OFF_W1T    = OFF_W01T + 1310720;
static const size_t OFF_W1GT   = OFF_W1T + 131072;
static const size_t OFF_GATEWT = OFF_W1GT + 131072;
static const size_t OFF_WMVT   = OFF_GATEWT + 262144;
static const size_t OFF_CTWT   = OFF_WMVT + 1048576;
static const size_t OFF_FFW1T  = OFF_CTWT + 524288;
static const size_t OFF_FFW2T  = OFF_FFW1T + 262144;
static const size_t WS_NEED    = OFF_FFW2T + 262144;

extern "C" void kernel_launch(void* const* d_in, const int* in_sizes, int n_in,
                              void* d_out, int out_size, void* d_ws, size_t ws_size,
                              hipStream_t stream) {
  if (ws_size < WS_NEED) return;

  const float* h       = (const float*)d_in[0];
  const float* gcn_w0  = (const float*)d_in[1];
  const float* gcn_b0  = (const float*)d_in[2];
  const float* gcn_w1  = (const float*)d_in[3];
  const float* gcn_b1  = (const float*)d_in[4];
  const float* bn_gcn0_g = (const float*)d_in[5];
  const float* bn_gcn0_b = (const float*)d_in[6];
  const float* bn_gcn1_g = (const float*)d_in[7];
  const float* bn_gcn1_b = (const float*)d_in[8];
  const float* gat_w0  = (const float*)d_in[9];
  const float* gat_al0 = (const float*)d_in[10];
  const float* gat_ar0 = (const float*)d_in[11];
  const float* gat_bias0 = (const float*)d_in[12];
  const float* gat_w1  = (const float*)d_in[13];
  const float* gat_al1 = (const float*)d_in[14];
  const float* gat_ar1 = (const float*)d_in[15];
  const float* gat_bias1 = (const float*)d_in[16];
  const float* bn_gat0_g = (const float*)d_in[17];
  const float* bn_gat0_b = (const float*)d_in[18];
  const float* bn_gat1_g = (const float*)d_in[19];
  const float* bn_gat1_b = (const float*)d_in[20];
  const float* gate_w  = (const float*)d_in[21];
  const float* gate_b  = (const float*)d_in[22];
  const float* qw      = (const float*)d_in[23];
  const float* kw      = (const float*)d_in[24];
  const float* vw      = (const float*)d_in[25];
  const float* ct_w    = (const float*)d_in[26];
  const float* ff_w1   = (const float*)d_in[27];
  const float* ff_b1   = (const float*)d_in[28];
  const float* ff_w2   = (const float*)d_in[29];
  const float* ff_b2   = (const float*)d_in[30];
  const float* ln_g    = (const float*)d_in[31];
  const float* ln_b    = (const float*)d_in[32];
  const int* srcv = (const int*)d_in[33];
  const int* dstv = (const int*)d_in[34];
  const int* gid  = (const int*)d_in[35];

  char* ws = (char*)d_ws;
  unsigned short* h_bf = (unsigned short*)(ws + OFF_BUFA);
  unsigned short* ff1o = (unsigned short*)(ws + OFF_BUFA);
  unsigned short* ff2o = (unsigned short*)(ws + OFF_BUFA + 51200000);
  unsigned short* c01  = (unsigned short*)(ws + OFF_C01);
  unsigned short* hg0  = (unsigned short*)(ws + OFF_HG0);
  unsigned short* ha0  = (unsigned short*)(ws + OFF_HA0);
  unsigned short* m1   = (unsigned short*)(ws + OFF_M1);
  unsigned short* f1   = (unsigned short*)(ws + OFF_F1);
  unsigned short* xcat = (unsigned short*)(ws + OFF_XCAT);
  unsigned short* xb   = (unsigned short*)(ws + OFF_XB);
  unsigned short* mo   = (unsigned short*)(ws + OFF_MO);
  unsigned short* x1   = (unsigned short*)(ws + OFF_X1);
  float* att           = (float*)(ws + OFF_ATT);
  float* alpha         = (float*)(ws + OFF_ALPHA);
  float* elr0          = (float*)(ws + OFF_ELR0);
  float* elr1          = (float*)(ws + OFF_ELR1);
  int* start   = (int*)(ws + OFF_START);
  int* deg_out = (int*)(ws + OFF_DEGO);
  int* deg_in  = (int*)(ws + OFF_DEGI);
  float* ns    = (float*)(ws + OFF_NS);
  float* nd    = (float*)(ws + OFF_ND);
  int* row_ptr = (int*)(ws + OFF_ROWP);
  int* fill    = (int*)(ws + OFF_FILL);
  int* bsum    = (int*)(ws + OFF_BSUM);
  int* boff    = (int*)(ws + OFF_BOFF);
  int* csr_src = (int*)(ws + OFF_CSRS);
  unsigned short* w01t   = (unsigned short*)(ws + OFF_W01T);
  unsigned short* w1t    = (unsigned short*)(ws + OFF_W1T);
  unsigned short* w1gt   = (unsigned short*)(ws + OFF_W1GT);
  unsigned short* gatewt = (unsigned short*)(ws + OFF_GATEWT);
  unsigned short* wmvt   = (unsigned short*)(ws + OFF_WMVT);
  unsigned short* w2t    = (unsigned short*)(ws + OFF_CTWT);
  unsigned short* ffw1t  = (unsigned short*)(ws + OFF_FFW1T);
  unsigned short* ffw2t  = (unsigned short*)(ws + OFF_FFW2T);

  float* out0 = (float*)d_out;            // readout [128,256]
  float* out1 = out0 + NG * HIDDEN;       // init_avg_h [128,1280]

  hipMemsetAsync(deg_out, 0, NN * 4, stream);
  hipMemsetAsync(deg_in, 0, NN * 4, stream);
  hipMemsetAsync(fill, 0, NN * 4, stream);
  hipMemsetAsync(out0, 0, NG * HIDDEN * 4, stream);
  hipMemsetAsync(out1, 0, NG * DIN * 4, stream);
  hipMemsetAsync(att, 0, NN * 4 * 4, stream);

  // weight prep
  transpose_w_k<<<(1280 * 256 + 255) / 256, 256, 0, stream>>>(gcn_w0, w01t, 1280, 256);
  transpose_w_k<<<(1280 * 256 + 255) / 256, 256, 0, stream>>>(gat_w0, w01t + 256 * 1280, 1280, 256);
  transpose_w_k<<<(256 * 256 + 255) / 256, 256, 0, stream>>>(gcn_w1, w1t, 256, 256);
  transpose_w_k<<<(256 * 256 + 255) / 256, 256, 0, stream>>>(gat_w1, w1gt, 256, 256);
  transpose_w_k<<<(512 * 256 + 255) / 256, 256, 0, stream>>>(gate_w, gatewt, 512, 256);
  mw_k<<<1024, 256, 0, stream>>>(qw, kw, wmvt);
  w2_k<<<1024, 256, 0, stream>>>(vw, ct_w, w2t);
  transpose_w_k<<<(256 * 512 + 255) / 256, 256, 0, stream>>>(ff_w1, ffw1t, 256, 512);
  transpose_w_k<<<(512 * 256 + 255) / 256, 256, 0, stream>>>(ff_w2, ffw2t, 512, 256);

  // graph structure
  graph_bounds_k<<<(NN + 255) / 256, 256, 0, stream>>>(gid, start, NN);
  degrees_k<<<(NE + 255) / 256, 256, 0, stream>>>(srcv, dstv, deg_out, deg_in, NE);
  invsqrt_k<<<(NN + 255) / 256, 256, 0, stream>>>(deg_out, deg_in, ns, nd, NN);
  const int NB_SCAN = (NN + 255) / 256;
  scan_local_k<<<NB_SCAN, 256, 0, stream>>>(deg_in, row_ptr, bsum);
  scan_bsum_k<<<1, 256, 0, stream>>>(bsum, boff, NB_SCAN, row_ptr);
  scan_add_k<<<NB_SCAN, 256, 0, stream>>>(row_ptr, boff);
  fill_csr_k<<<(NE + 255) / 256, 256, 0, stream>>>(srcv, dstv, row_ptr, fill, csr_src, NE);

  // fused h->bf16 + per-graph sums, then divide
  cvt_avg_k<<<NN / 50, 320, 0, stream>>>(h, gid, h_bf, out1);
  div_avg_k<<<(NG * DIN + 255) / 256, 256, 0, stream>>>(start, out1);

  const int MB = (NN + 127) / 128;
  // GEMM1: h @ [gcn_w0 | gat_w0] -> c01 [N,512] with fused elr0 (gat cols >=256)
  gemm_bf16<8><<<dim3(4, MB), 256, 0, stream>>>(h_bf, w01t, c01, nullptr, NN, 1280, 512,
                                                nullptr, nullptr, nullptr,
                                                gat_al0, gat_ar0, elr0, 256);
  gcn_agg_k<<<NN / 4, 256, 0, stream>>>(c01, 512, row_ptr, csr_src, ns, nd,
                                        gcn_b0, bn_gcn0_g, bn_gcn0_b, nullptr, 0, hg0, 256);
  gat_agg_k<<<NN / 4, 256, 0, stream>>>(c01 + 256, 512, row_ptr, csr_src, elr0,
                                        gat_bias0, bn_gat0_g, bn_gat0_b, nullptr, 0, ha0, 256);
  // layer 1: merged m1 (z=0) and f1+elr1 (z=1) GEMMs
  gemm_bf16<8><<<dim3(2, MB, 2), 256, 0, stream>>>(hg0, w1t, m1, nullptr, NN, 256, 256,
                                                   nullptr, nullptr, nullptr,
                                                   gat_al1, gat_ar1, elr1, 0);
  gcn_agg_k<<<NN / 4, 256, 0, stream>>>(m1, 256, row_ptr, csr_src, ns, nd,
                                        gcn_b1, bn_gcn1_g, bn_gcn1_b, hg0, 256, xcat, 512);
  gat_agg_k<<<NN / 4, 256, 0, stream>>>(f1, 256, row_ptr, csr_src, elr1,
                                        gat_bias1, bn_gat1_g, bn_gat1_b, ha0, 256, xcat + 256, 512);
  // gate GEMM with fused sigmoid-blend epilogue -> xb
  gemm_bf16<7><<<dim3(2, MB), 256, 0, stream>>>(xcat, gatewt, xb, gate_b, NN, 512, 256,
                                                xcat, nullptr, nullptr,
                                                nullptr, nullptr, nullptr, 0);
  // transformer: att = x^T M_h x via att epilogue (M-part only; V folded into W2)
  gemm_bf16<4><<<dim3(8, MB), 256, 0, stream>>>(xb, wmvt, nullptr, nullptr, NN, 256, 1024,
                                                xb, att, nullptr,
                                                nullptr, nullptr, nullptr, 0);
  gsoftmax_k<<<NG, 256, 0, stream>>>(att, start, alpha);
  // mo = (alpha-scaled xb, head-major K=1024) @ W2cat
  gemm_bf16<6><<<dim3(2, MB), 256, 0, stream>>>(xb, w2t, mo, nullptr, NN, 1024, 256,
                                                nullptr, nullptr, alpha,
                                                nullptr, nullptr, nullptr, 0);
  ln1_k<<<NN / 4, 256, 0, stream>>>(mo, xb, ln_g, ln_b, x1);
  gemm_bf16<2><<<dim3(4, MB), 256, 0, stream>>>(x1, ffw1t, ff1o, ff_b1, NN, 256, 512,
                                                nullptr, nullptr, nullptr,
                                                nullptr, nullptr, nullptr, 0);
  gemm_bf16<0><<<dim3(2, MB), 256, 0, stream>>>(ff1o, ffw2t, ff2o, nullptr, NN, 512, 256,
                                                nullptr, nullptr, nullptr,
                                                nullptr, nullptr, nullptr, 0);
  ln2_k<<<NN / 4, 256, 0, stream>>>(ff2o, ff_b2, x1, ln_g, ln_b, gid, out0);
}

// Round 4
// 1678.490 us; speedup vs baseline: 1.0900x; 1.0900x over previous
//
#include <hip/hip_runtime.h>

#define NN 50000
#define NE 800000
#define NG 128
#define DIN 1280
#define HIDDEN 256
#define BNS 0.9999950000374997f
#define ATT_SCALE 0.027950849718747373f
#define LN_EPS 1e-5f

typedef __attribute__((ext_vector_type(8))) short short8;
typedef __attribute__((ext_vector_type(4))) float floatx4;

__device__ __forceinline__ float b2f(unsigned short u) {
  return __uint_as_float(((unsigned int)u) << 16);
}
__device__ __forceinline__ unsigned short f2b(float f) {
  unsigned int x = __float_as_uint(f);
  x += 0x7fffu + ((x >> 16) & 1u);
  return (unsigned short)(x >> 16);
}

// ---------------- weight prep ----------------
__global__ void transpose_w_k(const float* __restrict__ src, unsigned short* __restrict__ dst,
                              int K, int Nc) {
  int idx = blockIdx.x * 256 + threadIdx.x;
  if (idx >= K * Nc) return;
  int n = idx / K, k = idx % K;
  dst[idx] = f2b(src[(size_t)k * Nc + n]);
}

// M_h = qw_h @ kw_h^T; dst rows [0,1024)
__global__ void mw_k(const float* __restrict__ qw, const float* __restrict__ kw,
                     unsigned short* __restrict__ dst) {
  int col = blockIdx.x;      // 0..1023
  int d = threadIdx.x;       // 0..255
  int hh = col >> 8, dp = col & 255;
  const float* qr = qw + ((size_t)hh * 256 + d) * 256;
  const float* kr = kw + ((size_t)hh * 256 + dp) * 256;
  float s = 0.f;
  for (int e = 0; e < 256; e += 4) {
    float4 a = *(const float4*)(qr + e);
    float4 b = *(const float4*)(kr + e);
    s += a.x * b.x + a.y * b.y + a.z * b.z + a.w * b.w;
  }
  dst[(size_t)col * 256 + d] = f2b(s);
}

// W2[h,d,c] = sum_e vw[h,d,e] * ctw[h*256+e, c];  Bt layout dst[c*1024 + h*256+d]
__global__ void w2_k(const float* __restrict__ vw, const float* __restrict__ ctw,
                     unsigned short* __restrict__ dst) {
  int b = blockIdx.x;        // k index: h*256+d
  int c = threadIdx.x;       // 0..255
  int hh = b >> 8, d = b & 255;
  const float* vr = vw + ((size_t)hh * 256 + d) * 256;
  float s = 0.f;
  for (int e = 0; e < 256; ++e)
    s += vr[e] * ctw[(size_t)(hh * 256 + e) * 256 + c];
  dst[(size_t)c * 1024 + b] = f2b(s);
}

// ---------------- fused h->bf16 conversion + per-graph sum (float4) ----------------
__global__ void cvt_avg_k(const float* __restrict__ h, const int* __restrict__ gid,
                          unsigned short* __restrict__ h_bf, float* __restrict__ out1) {
  int row0 = blockIdx.x * 50;
  int tid = threadIdx.x;     // 0..319
  float4 acc = {0.f, 0.f, 0.f, 0.f};
  int cur_g = gid[row0];
  int c4 = tid * 4;
  for (int r = 0; r < 50; ++r) {
    int row = row0 + r;
    int g = gid[row];
    if (g != cur_g) {
      atomicAdd(&out1[(size_t)cur_g * DIN + c4 + 0], acc.x);
      atomicAdd(&out1[(size_t)cur_g * DIN + c4 + 1], acc.y);
      atomicAdd(&out1[(size_t)cur_g * DIN + c4 + 2], acc.z);
      atomicAdd(&out1[(size_t)cur_g * DIN + c4 + 3], acc.w);
      acc = {0.f, 0.f, 0.f, 0.f};
      cur_g = g;
    }
    float4 v = *(const float4*)(h + (size_t)row * DIN + c4);
    acc.x += v.x; acc.y += v.y; acc.z += v.z; acc.w += v.w;
    ushort4 o;
    o.x = f2b(v.x); o.y = f2b(v.y); o.z = f2b(v.z); o.w = f2b(v.w);
    *(ushort4*)(h_bf + (size_t)row * DIN + c4) = o;
  }
  atomicAdd(&out1[(size_t)cur_g * DIN + c4 + 0], acc.x);
  atomicAdd(&out1[(size_t)cur_g * DIN + c4 + 1], acc.y);
  atomicAdd(&out1[(size_t)cur_g * DIN + c4 + 2], acc.z);
  atomicAdd(&out1[(size_t)cur_g * DIN + c4 + 3], acc.w);
}

__global__ void div_avg_k(const int* __restrict__ start, float* __restrict__ out1) {
  int idx = blockIdx.x * 256 + threadIdx.x;
  if (idx >= NG * DIN) return;
  int g = idx / DIN;
  float cnt = (float)(start[g + 1] - start[g]);
  if (cnt < 1.f) cnt = 1.f;
  out1[idx] /= cnt;
}

// ---------------- graph structure ----------------
__global__ void graph_bounds_k(const int* __restrict__ gid, int* __restrict__ start, int n) {
  int i = blockIdx.x * 256 + threadIdx.x;
  if (i >= n) return;
  int g = gid[i];
  if (i == 0) {
    for (int gg = 0; gg <= g; ++gg) start[gg] = 0;
  } else {
    int gp = gid[i - 1];
    for (int gg = gp + 1; gg <= g; ++gg) start[gg] = i;
  }
  if (i == n - 1) {
    for (int gg = g + 1; gg <= NG; ++gg) start[gg] = n;
  }
}

__global__ void degrees_k(const int* __restrict__ src, const int* __restrict__ dst,
                          int* __restrict__ deg_out, int* __restrict__ deg_in, int e) {
  int i = blockIdx.x * 256 + threadIdx.x;
  if (i >= e) return;
  atomicAdd(&deg_out[src[i]], 1);
  atomicAdd(&deg_in[dst[i]], 1);
}

__global__ void invsqrt_k(const int* __restrict__ deg_out, const int* __restrict__ deg_in,
                          float* __restrict__ ns, float* __restrict__ nd, int n) {
  int i = blockIdx.x * 256 + threadIdx.x;
  if (i >= n) return;
  int a = deg_out[i]; if (a < 1) a = 1;
  int b = deg_in[i];  if (b < 1) b = 1;
  ns[i] = rsqrtf((float)a);
  nd[i] = rsqrtf((float)b);
}

// 3-kernel scan: local scans, block-sum scan, add offsets
__global__ void scan_local_k(const int* __restrict__ deg, int* __restrict__ row_ptr,
                             int* __restrict__ bsum) {
  __shared__ int buf[256];
  int b = blockIdx.x, t = threadIdx.x;
  int i = b * 256 + t;
  int v = (i < NN) ? deg[i] : 0;
  buf[t] = v;
  __syncthreads();
  for (int off = 1; off < 256; off <<= 1) {
    int tv = (t >= off) ? buf[t - off] : 0;
    __syncthreads();
    buf[t] += tv;
    __syncthreads();
  }
  if (i < NN) row_ptr[i] = buf[t] - v;
  if (t == 255) bsum[b] = buf[255];
}

__global__ void scan_bsum_k(int* __restrict__ bsum, int* __restrict__ boff, int nb,
                            int* __restrict__ row_ptr) {
  __shared__ int buf[256];
  int t = threadIdx.x;
  int v = (t < nb) ? bsum[t] : 0;
  buf[t] = v;
  __syncthreads();
  for (int off = 1; off < 256; off <<= 1) {
    int tv = (t >= off) ? buf[t - off] : 0;
    __syncthreads();
    buf[t] += tv;
    __syncthreads();
  }
  if (t < nb) boff[t] = buf[t] - v;
  if (t == 0) row_ptr[NN] = NE;
}

__global__ void scan_add_k(int* __restrict__ row_ptr, const int* __restrict__ boff) {
  int i = blockIdx.x * 256 + threadIdx.x;
  if (i >= NN) return;
  row_ptr[i] += boff[blockIdx.x];
}

__global__ void fill_csr_k(const int* __restrict__ src, const int* __restrict__ dst,
                           const int* __restrict__ row_ptr, int* __restrict__ fill,
                           int* __restrict__ csr_src, int e) {
  int i = blockIdx.x * 256 + threadIdx.x;
  if (i >= e) return;
  int d = dst[i];
  int pos = row_ptr[d] + atomicAdd(&fill[d], 1);
  csr_src[pos] = src[i];
}

// ---------------- bf16 MFMA GEMM ----------------
// C[M,Nc] = A[M,K] * Bt[Nc,K]   (both bf16)
// LDS layout: cell(r,kb) = r*8 + (kb ^ (r&7)); double-buffered (2x32KB).
// Pipeline: stage(t+1) issued BEFORE compute(t); single __syncthreads per k-step.
// MODE 0: bf16 out; 1: fp32 out; 2: +bias relu bf16 out;
// MODE 4: att epilogue (quadratic form row-dot with xtile), no C store
// MODE 6: A synthesized as xb[gm, k&255] * ascale[gm*4 + (k>>8)] (reg-staged, single-buffer)
// MODE 7: gate epilogue: xb = sigmoid(acc+bias)*xcat[:,c] + (1-s)*xcat[:,256+c]
// MODE 8: bf16 out + fused el/er epilogue for gat cols (>= ecol0).
//         If gridDim.z==2: z=0 -> (hg0,w1t,m1) no elr; z=1 -> shifted ptrs (ha0,w1gt,f1) + elr.
template <int MODE>
__global__ __launch_bounds__(256, 2) void gemm_bf16(const unsigned short* __restrict__ A,
                                                    const unsigned short* __restrict__ Bt,
                                                    void* __restrict__ Cout,
                                                    const float* __restrict__ bias,
                                                    int M, int K, int Nc,
                                                    const unsigned short* __restrict__ xtile,
                                                    float* __restrict__ attp,
                                                    const float* __restrict__ ascale,
                                                    const float* __restrict__ al,
                                                    const float* __restrict__ ar,
                                                    float* __restrict__ elr,
                                                    int ecol0) {
  __shared__ unsigned short sbuf[32768];
  const int tid = threadIdx.x;
  const int n0 = blockIdx.x * 128;
  const int m0 = blockIdx.y * 128;
  const int w = tid >> 6;
  const int lane = tid & 63;
  const int wr = (w >> 1) * 64;
  const int wc = (w & 1) * 64;
  const int quad = lane >> 4;
  const int l15 = lane & 15;
  const int js = tid & 7;
  const int mbase = tid >> 3;
  const int wbase = w * 64;

  bool do_elr = (MODE == 8);
  const unsigned short* Ap = A;
  const unsigned short* Bp = Bt;
  unsigned short* Cp = (unsigned short*)Cout;
  if (MODE == 8 && gridDim.z == 2) {
    if (blockIdx.z == 0) {
      do_elr = false;
    } else {
      Ap += 12800000;   // ha0 - hg0 (ushorts)
      Bp += 65536;      // w1gt - w1t
      Cp += 12800000;   // f1 - m1
    }
  }

  floatx4 acc[4][4];
#pragma unroll
  for (int i = 0; i < 4; ++i)
#pragma unroll
    for (int j = 0; j < 4; ++j) acc[i][j] = (floatx4)0.0f;

  if constexpr (MODE == 6) {
    // single-buffered reg-staged path (A synthesized from xb * alpha)
    unsigned short* lA = sbuf;
    unsigned short* lB = sbuf + 8192;
    for (int k0 = 0; k0 < K; k0 += 64) {
      __syncthreads();
#pragma unroll
      for (int it = 0; it < 4; ++it) {
        int m = it * 32 + mbase;
        int gm = m0 + m;
        if (gm >= M) gm = M - 1;
        uint4 va = *(const uint4*)(Ap + (size_t)gm * 256 + (k0 & 255) + js * 8);
        float s = ascale[(size_t)gm * 4 + (k0 >> 8)];
        unsigned short* pp = (unsigned short*)&va;
#pragma unroll
        for (int c = 0; c < 8; ++c) pp[c] = f2b(b2f(pp[c]) * s);
        *(uint4*)(lA + (size_t)(m * 8 + (js ^ (m & 7))) * 8) = va;
      }
#pragma unroll
      for (int it = 0; it < 4; ++it) {
        int c = it * 256 + wbase + lane;
        int m = c >> 3, g = c & 7;
        int gn = n0 + m;
        const unsigned short* gp = Bp + (size_t)gn * K + k0 + (g ^ (m & 7)) * 8;
        __builtin_amdgcn_global_load_lds(
            (const __attribute__((address_space(1))) unsigned int*)gp,
            (__attribute__((address_space(3))) unsigned int*)(lB + (size_t)(it * 256 + wbase) * 8),
            16, 0, 0);
      }
      __syncthreads();
#pragma unroll
      for (int ks = 0; ks < 2; ++ks) {
        int kb = ks * 4 + quad;
        short8 af[4], bfr[4];
#pragma unroll
        for (int ri = 0; ri < 4; ++ri) {
          int r = wr + ri * 16 + l15;
          af[ri] = *(const short8*)(lA + (size_t)(r * 8 + (kb ^ (r & 7))) * 8);
        }
#pragma unroll
        for (int ci = 0; ci < 4; ++ci) {
          int c = wc + ci * 16 + l15;
          bfr[ci] = *(const short8*)(lB + (size_t)(c * 8 + (kb ^ (c & 7))) * 8);
        }
#pragma unroll
        for (int ri = 0; ri < 4; ++ri)
#pragma unroll
          for (int ci = 0; ci < 4; ++ci)
            acc[ri][ci] = __builtin_amdgcn_mfma_f32_16x16x32_bf16(af[ri], bfr[ci], acc[ri][ci], 0, 0, 0);
      }
    }
    __syncthreads();
  } else {
    const int nt = K >> 6;
    auto stage = [&](int b, int k0) {
      unsigned short* lA = sbuf + b * 16384;
      unsigned short* lB = lA + 8192;
#pragma unroll
      for (int it = 0; it < 4; ++it) {
        int c = it * 256 + wbase + lane;
        int m = c >> 3, g = c & 7;
        int gm = m0 + m;
        if (gm >= M) gm = M - 1;
        const unsigned short* gp = Ap + (size_t)gm * K + k0 + (g ^ (m & 7)) * 8;
        __builtin_amdgcn_global_load_lds(
            (const __attribute__((address_space(1))) unsigned int*)gp,
            (__attribute__((address_space(3))) unsigned int*)(lA + (size_t)(it * 256 + wbase) * 8),
            16, 0, 0);
      }
#pragma unroll
      for (int it = 0; it < 4; ++it) {
        int c = it * 256 + wbase + lane;
        int m = c >> 3, g = c & 7;
        int gn = n0 + m;
        const unsigned short* gp = Bp + (size_t)gn * K + k0 + (g ^ (m & 7)) * 8;
        __builtin_amdgcn_global_load_lds(
            (const __attribute__((address_space(1))) unsigned int*)gp,
            (__attribute__((address_space(3))) unsigned int*)(lB + (size_t)(it * 256 + wbase) * 8),
            16, 0, 0);
      }
    };
    stage(0, 0);
    __syncthreads();
    for (int t = 0; t < nt; ++t) {
      int cur = t & 1;
      if (t + 1 < nt) stage(cur ^ 1, (t + 1) * 64);
      unsigned short* lA = sbuf + cur * 16384;
      unsigned short* lB = lA + 8192;
#pragma unroll
      for (int ks = 0; ks < 2; ++ks) {
        int kb = ks * 4 + quad;
        short8 af[4], bfr[4];
#pragma unroll
        for (int ri = 0; ri < 4; ++ri) {
          int r = wr + ri * 16 + l15;
          af[ri] = *(const short8*)(lA + (size_t)(r * 8 + (kb ^ (r & 7))) * 8);
        }
#pragma unroll
        for (int ci = 0; ci < 4; ++ci) {
          int c = wc + ci * 16 + l15;
          bfr[ci] = *(const short8*)(lB + (size_t)(c * 8 + (kb ^ (c & 7))) * 8);
        }
#pragma unroll
        for (int ri = 0; ri < 4; ++ri)
#pragma unroll
          for (int ci = 0; ci < 4; ++ci)
            acc[ri][ci] = __builtin_amdgcn_mfma_f32_16x16x32_bf16(af[ri], bfr[ci], acc[ri][ci], 0, 0, 0);
      }
      __syncthreads();
    }
  }

  if (MODE == 4) {
    // att epilogue: att[n,h] += sum_col acc * xb[n,col]; no C store
    int cb = n0 & 255;
#pragma unroll
    for (int it2 = 0; it2 < 8; ++it2) {
      int linear = it2 * 256 + tid;
      int rr = linear >> 4;
      int c8 = (linear & 15) * 8;
      int gr = m0 + rr;
      if (gr >= M) gr = M - 1;
      *(uint4*)(sbuf + rr * 128 + c8) = *(const uint4*)(xtile + (size_t)gr * 256 + cb + c8);
    }
    __syncthreads();
    int head = n0 >> 8;
#pragma unroll
    for (int ri = 0; ri < 4; ++ri) {
      int lrow = wr + ri * 16 + quad * 4;
#pragma unroll
      for (int r = 0; r < 4; ++r) {
        float p = 0.f;
#pragma unroll
        for (int ci = 0; ci < 4; ++ci)
          p += acc[ri][ci][r] * b2f(sbuf[(lrow + r) * 128 + wc + ci * 16 + l15]);
        p += __shfl_xor(p, 1);
        p += __shfl_xor(p, 2);
        p += __shfl_xor(p, 4);
        p += __shfl_xor(p, 8);
        if (l15 == 0) {
          int grow = m0 + lrow + r;
          if (grow < M) atomicAdd(&attp[(size_t)grow * 4 + head], p * ATT_SCALE);
        }
      }
    }
    return;
  }

  if (MODE == 7) {
    // gate epilogue: g = sigmoid(acc + bias[col]); out = g*xcat[:,col] + (1-g)*xcat[:,256+col]
#pragma unroll
    for (int ri = 0; ri < 4; ++ri) {
      int row = m0 + wr + ri * 16 + quad * 4;
#pragma unroll
      for (int ci = 0; ci < 4; ++ci) {
        int col = n0 + wc + ci * 16 + l15;
        float bv = bias[col];
#pragma unroll
        for (int r = 0; r < 4; ++r) {
          if (row + r < M) {
            float g = 1.f / (1.f + expf(-(acc[ri][ci][r] + bv)));
            float hg = b2f(xtile[(size_t)(row + r) * 512 + col]);
            float ha = b2f(xtile[(size_t)(row + r) * 512 + 256 + col]);
            Cp[(size_t)(row + r) * Nc + col] = f2b(g * hg + (1.f - g) * ha);
          }
        }
      }
    }
    return;
  }

  if (MODE == 8 && do_elr && n0 >= ecol0) {
    // fused el/er: this wave's 64 cols are exactly one head's 64 dims
    int head = (n0 - ecol0 + wc) >> 6;
#pragma unroll
    for (int ri = 0; ri < 4; ++ri) {
      int lrow = wr + ri * 16 + quad * 4;
#pragma unroll
      for (int r = 0; r < 4; ++r) {
        float pl = 0.f, pr = 0.f;
#pragma unroll
        for (int ci = 0; ci < 4; ++ci) {
          float fv = acc[ri][ci][r];
          pl += fv * al[head * 64 + ci * 16 + l15];
          pr += fv * ar[head * 64 + ci * 16 + l15];
        }
        pl += __shfl_xor(pl, 1); pl += __shfl_xor(pl, 2);
        pl += __shfl_xor(pl, 4); pl += __shfl_xor(pl, 8);
        pr += __shfl_xor(pr, 1); pr += __shfl_xor(pr, 2);
        pr += __shfl_xor(pr, 4); pr += __shfl_xor(pr, 8);
        if (l15 == 0) {
          int grow = m0 + lrow + r;
          if (grow < M) {
            elr[(size_t)grow * 8 + head] = pl;
            elr[(size_t)grow * 8 + 4 + head] = pr;
          }
        }
      }
    }
  }

#pragma unroll
  for (int ri = 0; ri < 4; ++ri) {
    int row = m0 + wr + ri * 16 + quad * 4;
#pragma unroll
    for (int ci = 0; ci < 4; ++ci) {
      int col = n0 + wc + ci * 16 + l15;
      float bv = (MODE == 2) ? bias[col] : 0.f;
#pragma unroll
      for (int r = 0; r < 4; ++r) {
        if (row + r < M) {
          float v = acc[ri][ci][r];
          if (MODE == 2) { v += bv; v = fmaxf(v, 0.f); }
          if (MODE == 1)
            ((float*)Cout)[(size_t)(row + r) * Nc + col] = v;
          else
            Cp[(size_t)(row + r) * Nc + col] = f2b(v);
        }
      }
    }
  }
}

// ---------------- GCN aggregation ----------------
__global__ void gcn_agg_k(const unsigned short* __restrict__ m, int ldm,
                          const int* __restrict__ row_ptr, const int* __restrict__ csr_src,
                          const float* __restrict__ ns, const float* __restrict__ nd,
                          const float* __restrict__ bias,
                          const float* __restrict__ bng, const float* __restrict__ bnb,
                          const unsigned short* __restrict__ resid, int ldr,
                          unsigned short* __restrict__ out, int ldo) {
  int node = blockIdx.x * 4 + (threadIdx.x >> 6);
  if (node >= NN) return;
  int lane = threadIdx.x & 63;
  int s = row_ptr[node], e = row_ptr[node + 1];
  float a0 = 0, a1 = 0, a2 = 0, a3 = 0;
  for (int i = s; i < e; ++i) {
    int u = csr_src[i];
    float w = ns[u];
    ushort4 v = *(const ushort4*)(m + (size_t)u * ldm + lane * 4);
    a0 += w * b2f(v.x); a1 += w * b2f(v.y); a2 += w * b2f(v.z); a3 += w * b2f(v.w);
  }
  float ndv = nd[node];
  int col = lane * 4;
  float vals[4] = {a0, a1, a2, a3};
  ushort4 o;
#pragma unroll
  for (int c = 0; c < 4; ++c) {
    float v = vals[c] * ndv + bias[col + c];
    v = bng[col + c] * v * BNS + bnb[col + c];
    v = fmaxf(v, 0.f);
    if (resid) v += b2f(resid[(size_t)node * ldr + col + c]);
    ((unsigned short*)&o)[c] = f2b(v);
  }
  *(ushort4*)(out + (size_t)node * ldo + col) = o;
}

// ---------------- GAT aggregation ----------------
__global__ void gat_agg_k(const unsigned short* __restrict__ f, int ldf,
                          const int* __restrict__ row_ptr, const int* __restrict__ csr_src,
                          const float* __restrict__ elr,
                          const float* __restrict__ bias,
                          const float* __restrict__ bng, const float* __restrict__ bnb,
                          const unsigned short* __restrict__ resid, int ldr,
                          unsigned short* __restrict__ out, int ldo) {
  int node = blockIdx.x * 4 + (threadIdx.x >> 6);
  if (node >= NN) return;
  int lane = threadIdx.x & 63;
  int s = row_ptr[node], e = row_ptr[node + 1];
  float4 er = *(const float4*)(elr + (size_t)node * 8 + 4);
  float m0 = -1e30f, m1 = -1e30f, m2 = -1e30f, m3 = -1e30f;
  for (int i = s + lane; i < e; i += 64) {
    int u = csr_src[i];
    float4 el = *(const float4*)(elr + (size_t)u * 8);
    float t;
    t = el.x + er.x; t = t > 0.f ? t : 0.2f * t; m0 = fmaxf(m0, t);
    t = el.y + er.y; t = t > 0.f ? t : 0.2f * t; m1 = fmaxf(m1, t);
    t = el.z + er.z; t = t > 0.f ? t : 0.2f * t; m2 = fmaxf(m2, t);
    t = el.w + er.w; t = t > 0.f ? t : 0.2f * t; m3 = fmaxf(m3, t);
  }
#pragma unroll
  for (int off = 1; off < 64; off <<= 1) {
    m0 = fmaxf(m0, __shfl_xor(m0, off));
    m1 = fmaxf(m1, __shfl_xor(m1, off));
    m2 = fmaxf(m2, __shfl_xor(m2, off));
    m3 = fmaxf(m3, __shfl_xor(m3, off));
  }
  float s0 = 0, s1 = 0, s2 = 0, s3 = 0;
  for (int i = s + lane; i < e; i += 64) {
    int u = csr_src[i];
    float4 el = *(const float4*)(elr + (size_t)u * 8);
    float t;
    t = el.x + er.x; t = t > 0.f ? t : 0.2f * t; s0 += expf(t - m0);
    t = el.y + er.y; t = t > 0.f ? t : 0.2f * t; s1 += expf(t - m1);
    t = el.z + er.z; t = t > 0.f ? t : 0.2f * t; s2 += expf(t - m2);
    t = el.w + er.w; t = t > 0.f ? t : 0.2f * t; s3 += expf(t - m3);
  }
#pragma unroll
  for (int off = 1; off < 64; off <<= 1) {
    s0 += __shfl_xor(s0, off);
    s1 += __shfl_xor(s1, off);
    s2 += __shfl_xor(s2, off);
    s3 += __shfl_xor(s3, off);
  }
  int head = lane >> 4;
  float erh = head == 0 ? er.x : head == 1 ? er.y : head == 2 ? er.z : er.w;
  float mh = head == 0 ? m0 : head == 1 ? m1 : head == 2 ? m2 : m3;
  float sh = head == 0 ? s0 : head == 1 ? s1 : head == 2 ? s2 : s3;
  float inv_sh = (sh > 0.f) ? 1.f / sh : 0.f;
  float a0 = 0, a1 = 0, a2 = 0, a3 = 0;
  for (int i = s; i < e; ++i) {
    int u = csr_src[i];
    float t = elr[(size_t)u * 8 + head] + erh;
    t = t > 0.f ? t : 0.2f * t;
    float wgt = expf(t - mh) * inv_sh;
    ushort4 v = *(const ushort4*)(f + (size_t)u * ldf + lane * 4);
    a0 += wgt * b2f(v.x); a1 += wgt * b2f(v.y); a2 += wgt * b2f(v.z); a3 += wgt * b2f(v.w);
  }
  int col = lane * 4;
  float vals[4] = {a0, a1, a2, a3};
  ushort4 o;
#pragma unroll
  for (int c = 0; c < 4; ++c) {
    float v = vals[c] + bias[col + c];
    v = bng[col + c] * v * BNS + bnb[col + c];
    v = (v > 0.f) ? v : (expf(v) - 1.f);
    if (resid) v += b2f(resid[(size_t)node * ldr + col + c]);
    ((unsigned short*)&o)[c] = f2b(v);
  }
  *(ushort4*)(out + (size_t)node * ldo + col) = o;
}

// ---------------- per-graph node softmax ----------------
__global__ void gsoftmax_k(const float* __restrict__ att, const int* __restrict__ start,
                           float* __restrict__ alpha) {
  int g = blockIdx.x;
  int s = start[g], e = start[g + 1];
  int tid = threadIdx.x;
  __shared__ float red[256];
  __shared__ float mh[4], sh[4];
  float lm[4] = {-1e30f, -1e30f, -1e30f, -1e30f};
  for (int i = s + tid; i < e; i += 256) {
    float4 a = *(const float4*)(att + (size_t)i * 4);
    lm[0] = fmaxf(lm[0], a.x); lm[1] = fmaxf(lm[1], a.y);
    lm[2] = fmaxf(lm[2], a.z); lm[3] = fmaxf(lm[3], a.w);
  }
#pragma unroll
  for (int h = 0; h < 4; ++h) {
    red[tid] = lm[h]; __syncthreads();
    for (int off = 128; off > 0; off >>= 1) {
      if (tid < off) red[tid] = fmaxf(red[tid], red[tid + off]);
      __syncthreads();
    }
    if (tid == 0) mh[h] = red[0];
    __syncthreads();
  }
  float ls[4] = {0, 0, 0, 0};
  for (int i = s + tid; i < e; i += 256) {
    float4 a = *(const float4*)(att + (size_t)i * 4);
    ls[0] += expf(a.x - mh[0]); ls[1] += expf(a.y - mh[1]);
    ls[2] += expf(a.z - mh[2]); ls[3] += expf(a.w - mh[3]);
  }
#pragma unroll
  for (int h = 0; h < 4; ++h) {
    red[tid] = ls[h]; __syncthreads();
    for (int off = 128; off > 0; off >>= 1) {
      if (tid < off) red[tid] += red[tid + off];
      __syncthreads();
    }
    if (tid == 0) sh[h] = red[0];
    __syncthreads();
  }
  for (int i = s + tid; i < e; i += 256) {
    float4 a = *(const float4*)(att + (size_t)i * 4);
    float4 o;
    o.x = expf(a.x - mh[0]) / sh[0];
    o.y = expf(a.y - mh[1]) / sh[1];
    o.z = expf(a.z - mh[2]) / sh[2];
    o.w = expf(a.w - mh[3]) / sh[3];
    *(float4*)(alpha + (size_t)i * 4) = o;
  }
}

// ---------------- LayerNorms (all bf16 in/out) ----------------
__global__ void ln1_k(const unsigned short* __restrict__ mo, const unsigned short* __restrict__ x,
                      const float* __restrict__ g, const float* __restrict__ b,
                      unsigned short* __restrict__ x1) {
  int node = blockIdx.x * 4 + (threadIdx.x >> 6);
  if (node >= NN) return;
  int lane = threadIdx.x & 63;
  int c = lane * 4;
  ushort4 a = *(const ushort4*)(mo + (size_t)node * HIDDEN + c);
  ushort4 xx = *(const ushort4*)(x + (size_t)node * HIDDEN + c);
  float v0 = b2f(a.x) + b2f(xx.x), v1 = b2f(a.y) + b2f(xx.y);
  float v2 = b2f(a.z) + b2f(xx.z), v3 = b2f(a.w) + b2f(xx.w);
  float sm = v0 + v1 + v2 + v3;
#pragma unroll
  for (int off = 1; off < 64; off <<= 1) sm += __shfl_xor(sm, off);
  float mu = sm * (1.f / 256.f);
  float d0 = v0 - mu, d1 = v1 - mu, d2 = v2 - mu, d3 = v3 - mu;
  float sq = d0 * d0 + d1 * d1 + d2 * d2 + d3 * d3;
#pragma unroll
  for (int off = 1; off < 64; off <<= 1) sq += __shfl_xor(sq, off);
  float inv = rsqrtf(sq * (1.f / 256.f) + LN_EPS);
  ushort4 ob;
  ob.x = f2b(g[c + 0] * d0 * inv + b[c + 0]);
  ob.y = f2b(g[c + 1] * d1 * inv + b[c + 1]);
  ob.z = f2b(g[c + 2] * d2 * inv + b[c + 2]);
  ob.w = f2b(g[c + 3] * d3 * inv + b[c + 3]);
  *(ushort4*)(x1 + (size_t)node * HIDDEN + c) = ob;
}

__global__ void ln2_k(const unsigned short* __restrict__ ff2o, const float* __restrict__ ffb2,
                      const unsigned short* __restrict__ x1,
                      const float* __restrict__ g, const float* __restrict__ b,
                      unsigned short* __restrict__ x2) {
  int node = blockIdx.x * 4 + (threadIdx.x >> 6);
  if (node >= NN) return;
  int lane = threadIdx.x & 63;
  int c = lane * 4;
  ushort4 a = *(const ushort4*)(ff2o + (size_t)node * HIDDEN + c);
  ushort4 xx = *(const ushort4*)(x1 + (size_t)node * HIDDEN + c);
  float v0 = b2f(a.x) + ffb2[c + 0] + b2f(xx.x), v1 = b2f(a.y) + ffb2[c + 1] + b2f(xx.y);
  float v2 = b2f(a.z) + ffb2[c + 2] + b2f(xx.z), v3 = b2f(a.w) + ffb2[c + 3] + b2f(xx.w);
  float sm = v0 + v1 + v2 + v3;
#pragma unroll
  for (int off = 1; off < 64; off <<= 1) sm += __shfl_xor(sm, off);
  float mu = sm * (1.f / 256.f);
  float d0 = v0 - mu, d1 = v1 - mu, d2 = v2 - mu, d3 = v3 - mu;
  float sq = d0 * d0 + d1 * d1 + d2 * d2 + d3 * d3;
#pragma unroll
  for (int off = 1; off < 64; off <<= 1) sq += __shfl_xor(sq, off);
  float inv = rsqrtf(sq * (1.f / 256.f) + LN_EPS);
  ushort4 ob;
  ob.x = f2b(g[c + 0] * d0 * inv + b[c + 0]);
  ob.y = f2b(g[c + 1] * d1 * inv + b[c + 1]);
  ob.z = f2b(g[c + 2] * d2 * inv + b[c + 2]);
  ob.w = f2b(g[c + 3] * d3 * inv + b[c + 3]);
  *(ushort4*)(x2 + (size_t)node * HIDDEN + c) = ob;
}

// ---------------- readout (output 0) ----------------
__global__ void readout_k(const unsigned short* __restrict__ x2, const int* __restrict__ start,
                          float* __restrict__ out0) {
  int g = blockIdx.x;
  int c = threadIdx.x;
  float acc = 0.f;
  for (int i = start[g]; i < start[g + 1]; ++i) acc += b2f(x2[(size_t)i * HIDDEN + c]);
  out0[(size_t)g * HIDDEN + c] = acc;
}

// ---------------- workspace layout (bytes) ----------------
static const size_t OFF_BUFA   = 0;
static const size_t OFF_C01    = 128000000;
static const size_t OFF_HG0    = 179200000;
static const size_t OFF_HA0    = 204800000;
static const size_t OFF_M1     = 230400000;
static const size_t OFF_F1     = 256000000;
static const size_t OFF_XCAT   = 281600000;
static const size_t OFF_GLOGIT = 332800000;
static const size_t OFF_XB     = 358400000;
static const size_t OFF_MO     = 384000000;
static const size_t OFF_X1     = 409600000;
static const size_t OFF_ATT    = 435200000;
static const size_t OFF_ALPHA  = OFF_ATT + 800000;
static const size_t OFF_ELR0   = OFF_ALPHA + 800000;
static const size_t OFF_ELR1   = OFF_ELR0 + 1600000;
static const size_t OFF_START  = OFF_ELR1 + 1600000;
static const size_t OFF_DEGO   = OFF_START + 1024;
static const size_t OFF_DEGI   = OFF_DEGO + 200704;
static const size_t OFF_NS     = OFF_DEGI + 200704;
static const size_t OFF_ND     = OFF_NS + 200704;
static const size_t OFF_ROWP   = OFF_ND + 200704;
static const size_t OFF_FILL   = OFF_ROWP + 200704;
static const size_t OFF_BSUM   = OFF_FILL + 200704;
static const size_t OFF_BOFF   = OFF_BSUM + 1024;
static const size_t OFF_CSRS   = OFF_BOFF + 1024;
static const size_t OFF_W01T   = OFF_CSRS + 3200000;
static const size_t OFF_W1T    = OFF_W01T + 1310720;
static const size_t OFF_W1GT   = OFF_W1T + 131072;
static const size_t OFF_GATEWT = OFF_W1GT + 131072;
static const size_t OFF_WMVT   = OFF_GATEWT + 262144;
static const size_t OFF_CTWT   = OFF_WMVT + 1048576;
static const size_t OFF_FFW1T  = OFF_CTWT + 524288;
static const size_t OFF_FFW2T  = OFF_FFW1T + 262144;
static const size_t WS_NEED    = OFF_FFW2T + 262144;

extern "C" void kernel_launch(void* const* d_in, const int* in_sizes, int n_in,
                              void* d_out, int out_size, void* d_ws, size_t ws_size,
                              hipStream_t stream) {
  if (ws_size < WS_NEED) return;

  const float* h       = (const float*)d_in[0];
  const float* gcn_w0  = (const float*)d_in[1];
  const float* gcn_b0  = (const float*)d_in[2];
  const float* gcn_w1  = (const float*)d_in[3];
  const float* gcn_b1  = (const float*)d_in[4];
  const float* bn_gcn0_g = (const float*)d_in[5];
  const float* bn_gcn0_b = (const float*)d_in[6];
  const float* bn_gcn1_g = (const float*)d_in[7];
  const float* bn_gcn1_b = (const float*)d_in[8];
  const float* gat_w0  = (const float*)d_in[9];
  const float* gat_al0 = (const float*)d_in[10];
  const float* gat_ar0 = (const float*)d_in[11];
  const float* gat_bias0 = (const float*)d_in[12];
  const float* gat_w1  = (const float*)d_in[13];
  const float* gat_al1 = (const float*)d_in[14];
  const float* gat_ar1 = (const float*)d_in[15];
  const float* gat_bias1 = (const float*)d_in[16];
  const float* bn_gat0_g = (const float*)d_in[17];
  const float* bn_gat0_b = (const float*)d_in[18];
  const float* bn_gat1_g = (const float*)d_in[19];
  const float* bn_gat1_b = (const float*)d_in[20];
  const float* gate_w  = (const float*)d_in[21];
  const float* gate_b  = (const float*)d_in[22];
  const float* qw      = (const float*)d_in[23];
  const float* kw      = (const float*)d_in[24];
  const float* vw      = (const float*)d_in[25];
  const float* ct_w    = (const float*)d_in[26];
  const float* ff_w1   = (const float*)d_in[27];
  const float* ff_b1   = (const float*)d_in[28];
  const float* ff_w2   = (const float*)d_in[29];
  const float* ff_b2   = (const float*)d_in[30];
  const float* ln_g    = (const float*)d_in[31];
  const float* ln_b    = (const float*)d_in[32];
  const int* srcv = (const int*)d_in[33];
  const int* dstv = (const int*)d_in[34];
  const int* gid  = (const int*)d_in[35];

  char* ws = (char*)d_ws;
  unsigned short* h_bf = (unsigned short*)(ws + OFF_BUFA);
  unsigned short* ff1o = (unsigned short*)(ws + OFF_BUFA);
  unsigned short* ff2o = (unsigned short*)(ws + OFF_BUFA + 51200000);
  unsigned short* x2   = (unsigned short*)(ws + OFF_BUFA + 76800000);
  unsigned short* c01  = (unsigned short*)(ws + OFF_C01);
  unsigned short* hg0  = (unsigned short*)(ws + OFF_HG0);
  unsigned short* ha0  = (unsigned short*)(ws + OFF_HA0);
  unsigned short* m1   = (unsigned short*)(ws + OFF_M1);
  unsigned short* f1   = (unsigned short*)(ws + OFF_F1);
  unsigned short* xcat = (unsigned short*)(ws + OFF_XCAT);
  unsigned short* xb   = (unsigned short*)(ws + OFF_XB);
  unsigned short* mo   = (unsigned short*)(ws + OFF_MO);
  unsigned short* x1   = (unsigned short*)(ws + OFF_X1);
  float* att           = (float*)(ws + OFF_ATT);
  float* alpha         = (float*)(ws + OFF_ALPHA);
  float* elr0          = (float*)(ws + OFF_ELR0);
  float* elr1          = (float*)(ws + OFF_ELR1);
  int* start   = (int*)(ws + OFF_START);
  int* deg_out = (int*)(ws + OFF_DEGO);
  int* deg_in  = (int*)(ws + OFF_DEGI);
  float* ns    = (float*)(ws + OFF_NS);
  float* nd    = (float*)(ws + OFF_ND);
  int* row_ptr = (int*)(ws + OFF_ROWP);
  int* fill    = (int*)(ws + OFF_FILL);
  int* bsum    = (int*)(ws + OFF_BSUM);
  int* boff    = (int*)(ws + OFF_BOFF);
  int* csr_src = (int*)(ws + OFF_CSRS);
  unsigned short* w01t   = (unsigned short*)(ws + OFF_W01T);
  unsigned short* w1t    = (unsigned short*)(ws + OFF_W1T);
  unsigned short* w1gt   = (unsigned short*)(ws + OFF_W1GT);
  unsigned short* gatewt = (unsigned short*)(ws + OFF_GATEWT);
  unsigned short* wmvt   = (unsigned short*)(ws + OFF_WMVT);
  unsigned short* w2t    = (unsigned short*)(ws + OFF_CTWT);
  unsigned short* ffw1t  = (unsigned short*)(ws + OFF_FFW1T);
  unsigned short* ffw2t  = (unsigned short*)(ws + OFF_FFW2T);

  float* out0 = (float*)d_out;            // readout [128,256]
  float* out1 = out0 + NG * HIDDEN;       // init_avg_h [128,1280]

  hipMemsetAsync(deg_out, 0, NN * 4, stream);
  hipMemsetAsync(deg_in, 0, NN * 4, stream);
  hipMemsetAsync(fill, 0, NN * 4, stream);
  hipMemsetAsync(out1, 0, NG * DIN * 4, stream);
  hipMemsetAsync(att, 0, NN * 4 * 4, stream);

  // weight prep
  transpose_w_k<<<(1280 * 256 + 255) / 256, 256, 0, stream>>>(gcn_w0, w01t, 1280, 256);
  transpose_w_k<<<(1280 * 256 + 255) / 256, 256, 0, stream>>>(gat_w0, w01t + 256 * 1280, 1280, 256);
  transpose_w_k<<<(256 * 256 + 255) / 256, 256, 0, stream>>>(gcn_w1, w1t, 256, 256);
  transpose_w_k<<<(256 * 256 + 255) / 256, 256, 0, stream>>>(gat_w1, w1gt, 256, 256);
  transpose_w_k<<<(512 * 256 + 255) / 256, 256, 0, stream>>>(gate_w, gatewt, 512, 256);
  mw_k<<<1024, 256, 0, stream>>>(qw, kw, wmvt);
  w2_k<<<1024, 256, 0, stream>>>(vw, ct_w, w2t);
  transpose_w_k<<<(256 * 512 + 255) / 256, 256, 0, stream>>>(ff_w1, ffw1t, 256, 512);
  transpose_w_k<<<(512 * 256 + 255) / 256, 256, 0, stream>>>(ff_w2, ffw2t, 512, 256);

  // graph structure
  graph_bounds_k<<<(NN + 255) / 256, 256, 0, stream>>>(gid, start, NN);
  degrees_k<<<(NE + 255) / 256, 256, 0, stream>>>(srcv, dstv, deg_out, deg_in, NE);
  invsqrt_k<<<(NN + 255) / 256, 256, 0, stream>>>(deg_out, deg_in, ns, nd, NN);
  const int NB_SCAN = (NN + 255) / 256;
  scan_local_k<<<NB_SCAN, 256, 0, stream>>>(deg_in, row_ptr, bsum);
  scan_bsum_k<<<1, 256, 0, stream>>>(bsum, boff, NB_SCAN, row_ptr);
  scan_add_k<<<NB_SCAN, 256, 0, stream>>>(row_ptr, boff);
  fill_csr_k<<<(NE + 255) / 256, 256, 0, stream>>>(srcv, dstv, row_ptr, fill, csr_src, NE);

  // fused h->bf16 + per-graph sums, then divide
  cvt_avg_k<<<NN / 50, 320, 0, stream>>>(h, gid, h_bf, out1);
  div_avg_k<<<(NG * DIN + 255) / 256, 256, 0, stream>>>(start, out1);

  const int MB = (NN + 127) / 128;
  // GEMM1: h @ [gcn_w0 | gat_w0] -> c01 [N,512] with fused elr0 (gat cols >=256)
  gemm_bf16<8><<<dim3(4, MB), 256, 0, stream>>>(h_bf, w01t, c01, nullptr, NN, 1280, 512,
                                                nullptr, nullptr, nullptr,
                                                gat_al0, gat_ar0, elr0, 256);
  gcn_agg_k<<<NN / 4, 256, 0, stream>>>(c01, 512, row_ptr, csr_src, ns, nd,
                                        gcn_b0, bn_gcn0_g, bn_gcn0_b, nullptr, 0, hg0, 256);
  gat_agg_k<<<NN / 4, 256, 0, stream>>>(c01 + 256, 512, row_ptr, csr_src, elr0,
                                        gat_bias0, bn_gat0_g, bn_gat0_b, nullptr, 0, ha0, 256);
  // layer 1: merged m1 (z=0) and f1+elr1 (z=1) GEMMs
  gemm_bf16<8><<<dim3(2, MB, 2), 256, 0, stream>>>(hg0, w1t, m1, nullptr, NN, 256, 256,
                                                   nullptr, nullptr, nullptr,
                                                   gat_al1, gat_ar1, elr1, 0);
  gcn_agg_k<<<NN / 4, 256, 0, stream>>>(m1, 256, row_ptr, csr_src, ns, nd,
                                        gcn_b1, bn_gcn1_g, bn_gcn1_b, hg0, 256, xcat, 512);
  gat_agg_k<<<NN / 4, 256, 0, stream>>>(f1, 256, row_ptr, csr_src, elr1,
                                        gat_bias1, bn_gat1_g, bn_gat1_b, ha0, 256, xcat + 256, 512);
  // gate GEMM with fused sigmoid-blend epilogue -> xb
  gemm_bf16<7><<<dim3(2, MB), 256, 0, stream>>>(xcat, gatewt, xb, gate_b, NN, 512, 256,
                                                xcat, nullptr, nullptr,
                                                nullptr, nullptr, nullptr, 0);
  // transformer: att = x^T M_h x via att epilogue (M-part only; V folded into W2)
  gemm_bf16<4><<<dim3(8, MB), 256, 0, stream>>>(xb, wmvt, nullptr, nullptr, NN, 256, 1024,
                                                xb, att, nullptr,
                                                nullptr, nullptr, nullptr, 0);
  gsoftmax_k<<<NG, 256, 0, stream>>>(att, start, alpha);
  // mo = (alpha-scaled xb, head-major K=1024) @ W2cat
  gemm_bf16<6><<<dim3(2, MB), 256, 0, stream>>>(xb, w2t, mo, nullptr, NN, 1024, 256,
                                                nullptr, nullptr, alpha,
                                                nullptr, nullptr, nullptr, 0);
  ln1_k<<<NN / 4, 256, 0, stream>>>(mo, xb, ln_g, ln_b, x1);
  gemm_bf16<2><<<dim3(4, MB), 256, 0, stream>>>(x1, ffw1t, ff1o, ff_b1, NN, 256, 512,
                                                nullptr, nullptr, nullptr,
                                                nullptr, nullptr, nullptr, 0);
  gemm_bf16<0><<<dim3(2, MB), 256, 0, stream>>>(ff1o, ffw2t, ff2o, nullptr, NN, 512, 256,
                                                nullptr, nullptr, nullptr,
                                                nullptr, nullptr, nullptr, 0);
  ln2_k<<<NN / 4, 256, 0, stream>>>(ff2o, ff_b2, x1, ln_g, ln_b, x2);
  readout_k<<<NG, 256, 0, stream>>>(x2, start, out0);
}

// Round 5
// 1575.766 us; speedup vs baseline: 1.1610x; 1.0652x over previous
//
#include <hip/hip_runtime.h>

#define NN 50000
#define NE 800000
#define NG 128
#define DIN 1280
#define HIDDEN 256
#define BNS 0.9999950000374997f
#define ATT_SCALE 0.027950849718747373f
#define LN_EPS 1e-5f

typedef __attribute__((ext_vector_type(8))) short short8;
typedef __attribute__((ext_vector_type(4))) float floatx4;

__device__ __forceinline__ float b2f(unsigned short u) {
  return __uint_as_float(((unsigned int)u) << 16);
}
__device__ __forceinline__ unsigned short f2b(float f) {
  unsigned int x = __float_as_uint(f);
  x += 0x7fffu + ((x >> 16) & 1u);
  return (unsigned short)(x >> 16);
}

// ---------------- merged weight prep (one dispatch) ----------------
__device__ __forceinline__ void tr_dev(const float* __restrict__ src,
                                       unsigned short* __restrict__ dst,
                                       int K, int Nc, int bi) {
  int idx = bi * 256 + threadIdx.x;
  if (idx >= K * Nc) return;
  int n = idx / K, k = idx % K;
  dst[idx] = f2b(src[(size_t)k * Nc + n]);
}

// block ranges:
// [0,1280) gcn_w0->w01t | [1280,2560) gat_w0->w01t+256*1280 | [2560,2816) gcn_w1->w1t
// [2816,3072) gat_w1->w1gt | [3072,3584) gate_w->gatewt | [3584,4096) ff_w1->ffw1t
// [4096,4608) ff_w2->ffw2t | [4608,5632) mw (qw@kw^T)->wmvt | [5632,6656) w2 (vw@ctw)->w2t
__global__ void prep_all_k(const float* __restrict__ gcn_w0, const float* __restrict__ gat_w0,
                           const float* __restrict__ gcn_w1, const float* __restrict__ gat_w1,
                           const float* __restrict__ gate_w, const float* __restrict__ ff_w1,
                           const float* __restrict__ ff_w2, const float* __restrict__ qw,
                           const float* __restrict__ kw, const float* __restrict__ vw,
                           const float* __restrict__ ctw,
                           unsigned short* __restrict__ w01t, unsigned short* __restrict__ w1t,
                           unsigned short* __restrict__ w1gt, unsigned short* __restrict__ gatewt,
                           unsigned short* __restrict__ ffw1t, unsigned short* __restrict__ ffw2t,
                           unsigned short* __restrict__ wmvt, unsigned short* __restrict__ w2t) {
  int b = blockIdx.x;
  if (b < 1280) { tr_dev(gcn_w0, w01t, 1280, 256, b); return; }
  if (b < 2560) { tr_dev(gat_w0, w01t + 256 * 1280, 1280, 256, b - 1280); return; }
  if (b < 2816) { tr_dev(gcn_w1, w1t, 256, 256, b - 2560); return; }
  if (b < 3072) { tr_dev(gat_w1, w1gt, 256, 256, b - 2816); return; }
  if (b < 3584) { tr_dev(gate_w, gatewt, 512, 256, b - 3072); return; }
  if (b < 4096) { tr_dev(ff_w1, ffw1t, 256, 512, b - 3584); return; }
  if (b < 4608) { tr_dev(ff_w2, ffw2t, 512, 256, b - 4096); return; }
  if (b < 5632) {
    int col = b - 4608;
    int d = threadIdx.x;
    int hh = col >> 8, dp = col & 255;
    const float* qr = qw + ((size_t)hh * 256 + d) * 256;
    const float* kr = kw + ((size_t)hh * 256 + dp) * 256;
    float s = 0.f;
    for (int e = 0; e < 256; e += 4) {
      float4 a = *(const float4*)(qr + e);
      float4 bb = *(const float4*)(kr + e);
      s += a.x * bb.x + a.y * bb.y + a.z * bb.z + a.w * bb.w;
    }
    wmvt[(size_t)col * 256 + d] = f2b(s);
    return;
  }
  {
    int bb = b - 5632;
    int c = threadIdx.x;
    int hh = bb >> 8, d = bb & 255;
    const float* vr = vw + ((size_t)hh * 256 + d) * 256;
    float s = 0.f;
    for (int e = 0; e < 256; ++e)
      s += vr[e] * ctw[(size_t)(hh * 256 + e) * 256 + c];
    w2t[(size_t)c * 1024 + bb] = f2b(s);
  }
}

// ---------------- fused h->bf16 conversion + per-graph sum (float4) ----------------
__global__ void cvt_avg_k(const float* __restrict__ h, const int* __restrict__ gid,
                          unsigned short* __restrict__ h_bf, float* __restrict__ out1) {
  int row0 = blockIdx.x * 50;
  int tid = threadIdx.x;     // 0..319
  float4 acc = {0.f, 0.f, 0.f, 0.f};
  int cur_g = gid[row0];
  int c4 = tid * 4;
  for (int r = 0; r < 50; ++r) {
    int row = row0 + r;
    int g = gid[row];
    if (g != cur_g) {
      atomicAdd(&out1[(size_t)cur_g * DIN + c4 + 0], acc.x);
      atomicAdd(&out1[(size_t)cur_g * DIN + c4 + 1], acc.y);
      atomicAdd(&out1[(size_t)cur_g * DIN + c4 + 2], acc.z);
      atomicAdd(&out1[(size_t)cur_g * DIN + c4 + 3], acc.w);
      acc = {0.f, 0.f, 0.f, 0.f};
      cur_g = g;
    }
    float4 v = *(const float4*)(h + (size_t)row * DIN + c4);
    acc.x += v.x; acc.y += v.y; acc.z += v.z; acc.w += v.w;
    ushort4 o;
    o.x = f2b(v.x); o.y = f2b(v.y); o.z = f2b(v.z); o.w = f2b(v.w);
    *(ushort4*)(h_bf + (size_t)row * DIN + c4) = o;
  }
  atomicAdd(&out1[(size_t)cur_g * DIN + c4 + 0], acc.x);
  atomicAdd(&out1[(size_t)cur_g * DIN + c4 + 1], acc.y);
  atomicAdd(&out1[(size_t)cur_g * DIN + c4 + 2], acc.z);
  atomicAdd(&out1[(size_t)cur_g * DIN + c4 + 3], acc.w);
}

__global__ void div_avg_k(const int* __restrict__ start, float* __restrict__ out1) {
  int idx = blockIdx.x * 256 + threadIdx.x;
  if (idx >= NG * DIN) return;
  int g = idx / DIN;
  float cnt = (float)(start[g + 1] - start[g]);
  if (cnt < 1.f) cnt = 1.f;
  out1[idx] /= cnt;
}

// ---------------- graph structure (merged) ----------------
__global__ void bounds_deg_k(const int* __restrict__ gid, int* __restrict__ start,
                             const int* __restrict__ src, const int* __restrict__ dst,
                             int* __restrict__ deg_out, int* __restrict__ deg_in) {
  int i = blockIdx.x * 256 + threadIdx.x;
  if (i < NN) {
    int g = gid[i];
    if (i == 0) {
      for (int gg = 0; gg <= g; ++gg) start[gg] = 0;
    } else {
      int gp = gid[i - 1];
      for (int gg = gp + 1; gg <= g; ++gg) start[gg] = i;
    }
    if (i == NN - 1) {
      for (int gg = g + 1; gg <= NG; ++gg) start[gg] = NN;
    }
  }
  if (i < NE) {
    atomicAdd(&deg_out[src[i]], 1);
    atomicAdd(&deg_in[dst[i]], 1);
  }
}

// local scan of deg_in + fused ns/nd computation
__global__ void scan_local_k(const int* __restrict__ deg_in, const int* __restrict__ deg_out,
                             int* __restrict__ row_ptr, int* __restrict__ bsum,
                             float* __restrict__ ns, float* __restrict__ nd) {
  __shared__ int buf[256];
  int b = blockIdx.x, t = threadIdx.x;
  int i = b * 256 + t;
  int v = (i < NN) ? deg_in[i] : 0;
  buf[t] = v;
  __syncthreads();
  for (int off = 1; off < 256; off <<= 1) {
    int tv = (t >= off) ? buf[t - off] : 0;
    __syncthreads();
    buf[t] += tv;
    __syncthreads();
  }
  if (i < NN) {
    row_ptr[i] = buf[t] - v;
    int a = deg_out[i]; if (a < 1) a = 1;
    int bb = v;         if (bb < 1) bb = 1;
    ns[i] = rsqrtf((float)a);
    nd[i] = rsqrtf((float)bb);
  }
  if (t == 255) bsum[b] = buf[255];
}

__global__ void scan_bsum_k(int* __restrict__ bsum, int* __restrict__ boff, int nb,
                            int* __restrict__ row_ptr) {
  __shared__ int buf[256];
  int t = threadIdx.x;
  int v = (t < nb) ? bsum[t] : 0;
  buf[t] = v;
  __syncthreads();
  for (int off = 1; off < 256; off <<= 1) {
    int tv = (t >= off) ? buf[t - off] : 0;
    __syncthreads();
    buf[t] += tv;
    __syncthreads();
  }
  if (t < nb) boff[t] = buf[t] - v;
  if (t == 0) row_ptr[NN] = NE;
}

__global__ void scan_add_k(int* __restrict__ row_ptr, const int* __restrict__ boff) {
  int i = blockIdx.x * 256 + threadIdx.x;
  if (i >= NN) return;
  row_ptr[i] += boff[blockIdx.x];
}

__global__ void fill_csr_k(const int* __restrict__ src, const int* __restrict__ dst,
                           const int* __restrict__ row_ptr, int* __restrict__ fill,
                           int* __restrict__ csr_src, int e) {
  int i = blockIdx.x * 256 + threadIdx.x;
  if (i >= e) return;
  int d = dst[i];
  int pos = row_ptr[d] + atomicAdd(&fill[d], 1);
  csr_src[pos] = src[i];
}

// ---------------- bf16 MFMA GEMM ----------------
// C[M,Nc] = A[M,K] * Bt[Nc,K]   (both bf16)
// LDS layout: cell(r,kb) = r*8 + (kb ^ (r&7)); double-buffered (2x32KB).
// MODE 0: bf16 out; 1: fp32 out; 2: +bias relu bf16 out;
// MODE 4: att epilogue (quadratic form row-dot with xtile), no C store
// MODE 6: A synthesized as xb[gm, k&255] * ascale[gm*4 + (k>>8)] (reg-staged, single-buffer)
// MODE 7: gate epilogue: xb = sigmoid(acc+bias)*xcat[:,c] + (1-s)*xcat[:,256+c]
// MODE 8: bf16 out + fused el/er epilogue for gat cols (>= ecol0).
//         If gridDim.z==2: z=0 -> (hg0,w1t,m1) no elr; z=1 -> shifted ptrs (ha0,w1gt,f1) + elr.
template <int MODE>
__global__ __launch_bounds__(256, 2) void gemm_bf16(const unsigned short* __restrict__ A,
                                                    const unsigned short* __restrict__ Bt,
                                                    void* __restrict__ Cout,
                                                    const float* __restrict__ bias,
                                                    int M, int K, int Nc,
                                                    const unsigned short* __restrict__ xtile,
                                                    float* __restrict__ attp,
                                                    const float* __restrict__ ascale,
                                                    const float* __restrict__ al,
                                                    const float* __restrict__ ar,
                                                    float* __restrict__ elr,
                                                    int ecol0) {
  __shared__ unsigned short sbuf[32768];
  const int tid = threadIdx.x;
  const int n0 = blockIdx.x * 128;
  const int m0 = blockIdx.y * 128;
  const int w = tid >> 6;
  const int lane = tid & 63;
  const int wr = (w >> 1) * 64;
  const int wc = (w & 1) * 64;
  const int quad = lane >> 4;
  const int l15 = lane & 15;
  const int js = tid & 7;
  const int mbase = tid >> 3;
  const int wbase = w * 64;

  bool do_elr = (MODE == 8);
  const unsigned short* Ap = A;
  const unsigned short* Bp = Bt;
  unsigned short* Cp = (unsigned short*)Cout;
  if (MODE == 8 && gridDim.z == 2) {
    if (blockIdx.z == 0) {
      do_elr = false;
    } else {
      Ap += 12800000;   // ha0 - hg0 (ushorts)
      Bp += 65536;      // w1gt - w1t
      Cp += 12800000;   // f1 - m1
    }
  }

  floatx4 acc[4][4];
#pragma unroll
  for (int i = 0; i < 4; ++i)
#pragma unroll
    for (int j = 0; j < 4; ++j) acc[i][j] = (floatx4)0.0f;

  if constexpr (MODE == 6) {
    // single-buffered reg-staged path (A synthesized from xb * alpha)
    unsigned short* lA = sbuf;
    unsigned short* lB = sbuf + 8192;
    for (int k0 = 0; k0 < K; k0 += 64) {
      __syncthreads();
#pragma unroll
      for (int it = 0; it < 4; ++it) {
        int m = it * 32 + mbase;
        int gm = m0 + m;
        if (gm >= M) gm = M - 1;
        uint4 va = *(const uint4*)(Ap + (size_t)gm * 256 + (k0 & 255) + js * 8);
        float s = ascale[(size_t)gm * 4 + (k0 >> 8)];
        unsigned short* pp = (unsigned short*)&va;
#pragma unroll
        for (int c = 0; c < 8; ++c) pp[c] = f2b(b2f(pp[c]) * s);
        *(uint4*)(lA + (size_t)(m * 8 + (js ^ (m & 7))) * 8) = va;
      }
#pragma unroll
      for (int it = 0; it < 4; ++it) {
        int c = it * 256 + wbase + lane;
        int m = c >> 3, g = c & 7;
        int gn = n0 + m;
        const unsigned short* gp = Bp + (size_t)gn * K + k0 + (g ^ (m & 7)) * 8;
        __builtin_amdgcn_global_load_lds(
            (const __attribute__((address_space(1))) unsigned int*)gp,
            (__attribute__((address_space(3))) unsigned int*)(lB + (size_t)(it * 256 + wbase) * 8),
            16, 0, 0);
      }
      __syncthreads();
#pragma unroll
      for (int ks = 0; ks < 2; ++ks) {
        int kb = ks * 4 + quad;
        short8 af[4], bfr[4];
#pragma unroll
        for (int ri = 0; ri < 4; ++ri) {
          int r = wr + ri * 16 + l15;
          af[ri] = *(const short8*)(lA + (size_t)(r * 8 + (kb ^ (r & 7))) * 8);
        }
#pragma unroll
        for (int ci = 0; ci < 4; ++ci) {
          int c = wc + ci * 16 + l15;
          bfr[ci] = *(const short8*)(lB + (size_t)(c * 8 + (kb ^ (c & 7))) * 8);
        }
#pragma unroll
        for (int ri = 0; ri < 4; ++ri)
#pragma unroll
          for (int ci = 0; ci < 4; ++ci)
            acc[ri][ci] = __builtin_amdgcn_mfma_f32_16x16x32_bf16(af[ri], bfr[ci], acc[ri][ci], 0, 0, 0);
      }
    }
    __syncthreads();
  } else {
    const int nt = K >> 6;
    auto stage = [&](int b, int k0) {
      unsigned short* lA = sbuf + b * 16384;
      unsigned short* lB = lA + 8192;
#pragma unroll
      for (int it = 0; it < 4; ++it) {
        int c = it * 256 + wbase + lane;
        int m = c >> 3, g = c & 7;
        int gm = m0 + m;
        if (gm >= M) gm = M - 1;
        const unsigned short* gp = Ap + (size_t)gm * K + k0 + (g ^ (m & 7)) * 8;
        __builtin_amdgcn_global_load_lds(
            (const __attribute__((address_space(1))) unsigned int*)gp,
            (__attribute__((address_space(3))) unsigned int*)(lA + (size_t)(it * 256 + wbase) * 8),
            16, 0, 0);
      }
#pragma unroll
      for (int it = 0; it < 4; ++it) {
        int c = it * 256 + wbase + lane;
        int m = c >> 3, g = c & 7;
        int gn = n0 + m;
        const unsigned short* gp = Bp + (size_t)gn * K + k0 + (g ^ (m & 7)) * 8;
        __builtin_amdgcn_global_load_lds(
            (const __attribute__((address_space(1))) unsigned int*)gp,
            (__attribute__((address_space(3))) unsigned int*)(lB + (size_t)(it * 256 + wbase) * 8),
            16, 0, 0);
      }
    };
    stage(0, 0);
    __syncthreads();
    for (int t = 0; t < nt; ++t) {
      int cur = t & 1;
      if (t + 1 < nt) stage(cur ^ 1, (t + 1) * 64);
      unsigned short* lA = sbuf + cur * 16384;
      unsigned short* lB = lA + 8192;
#pragma unroll
      for (int ks = 0; ks < 2; ++ks) {
        int kb = ks * 4 + quad;
        short8 af[4], bfr[4];
#pragma unroll
        for (int ri = 0; ri < 4; ++ri) {
          int r = wr + ri * 16 + l15;
          af[ri] = *(const short8*)(lA + (size_t)(r * 8 + (kb ^ (r & 7))) * 8);
        }
#pragma unroll
        for (int ci = 0; ci < 4; ++ci) {
          int c = wc + ci * 16 + l15;
          bfr[ci] = *(const short8*)(lB + (size_t)(c * 8 + (kb ^ (c & 7))) * 8);
        }
#pragma unroll
        for (int ri = 0; ri < 4; ++ri)
#pragma unroll
          for (int ci = 0; ci < 4; ++ci)
            acc[ri][ci] = __builtin_amdgcn_mfma_f32_16x16x32_bf16(af[ri], bfr[ci], acc[ri][ci], 0, 0, 0);
      }
      __syncthreads();
    }
  }

  if (MODE == 4) {
    // att epilogue: att[n,h] += sum_col acc * xb[n,col]; no C store
    int cb = n0 & 255;
#pragma unroll
    for (int it2 = 0; it2 < 8; ++it2) {
      int linear = it2 * 256 + tid;
      int rr = linear >> 4;
      int c8 = (linear & 15) * 8;
      int gr = m0 + rr;
      if (gr >= M) gr = M - 1;
      *(uint4*)(sbuf + rr * 128 + c8) = *(const uint4*)(xtile + (size_t)gr * 256 + cb + c8);
    }
    __syncthreads();
    int head = n0 >> 8;
#pragma unroll
    for (int ri = 0; ri < 4; ++ri) {
      int lrow = wr + ri * 16 + quad * 4;
#pragma unroll
      for (int r = 0; r < 4; ++r) {
        float p = 0.f;
#pragma unroll
        for (int ci = 0; ci < 4; ++ci)
          p += acc[ri][ci][r] * b2f(sbuf[(lrow + r) * 128 + wc + ci * 16 + l15]);
        p += __shfl_xor(p, 1);
        p += __shfl_xor(p, 2);
        p += __shfl_xor(p, 4);
        p += __shfl_xor(p, 8);
        if (l15 == 0) {
          int grow = m0 + lrow + r;
          if (grow < M) atomicAdd(&attp[(size_t)grow * 4 + head], p * ATT_SCALE);
        }
      }
    }
    return;
  }

  if (MODE == 7) {
    // gate epilogue
#pragma unroll
    for (int ri = 0; ri < 4; ++ri) {
      int row = m0 + wr + ri * 16 + quad * 4;
#pragma unroll
      for (int ci = 0; ci < 4; ++ci) {
        int col = n0 + wc + ci * 16 + l15;
        float bv = bias[col];
#pragma unroll
        for (int r = 0; r < 4; ++r) {
          if (row + r < M) {
            float g = 1.f / (1.f + expf(-(acc[ri][ci][r] + bv)));
            float hg = b2f(xtile[(size_t)(row + r) * 512 + col]);
            float ha = b2f(xtile[(size_t)(row + r) * 512 + 256 + col]);
            Cp[(size_t)(row + r) * Nc + col] = f2b(g * hg + (1.f - g) * ha);
          }
        }
      }
    }
    return;
  }

  if (MODE == 8 && do_elr && n0 >= ecol0) {
    // fused el/er: this wave's 64 cols are exactly one head's 64 dims
    int head = (n0 - ecol0 + wc) >> 6;
#pragma unroll
    for (int ri = 0; ri < 4; ++ri) {
      int lrow = wr + ri * 16 + quad * 4;
#pragma unroll
      for (int r = 0; r < 4; ++r) {
        float pl = 0.f, pr = 0.f;
#pragma unroll
        for (int ci = 0; ci < 4; ++ci) {
          float fv = acc[ri][ci][r];
          pl += fv * al[head * 64 + ci * 16 + l15];
          pr += fv * ar[head * 64 + ci * 16 + l15];
        }
        pl += __shfl_xor(pl, 1); pl += __shfl_xor(pl, 2);
        pl += __shfl_xor(pl, 4); pl += __shfl_xor(pl, 8);
        pr += __shfl_xor(pr, 1); pr += __shfl_xor(pr, 2);
        pr += __shfl_xor(pr, 4); pr += __shfl_xor(pr, 8);
        if (l15 == 0) {
          int grow = m0 + lrow + r;
          if (grow < M) {
            elr[(size_t)grow * 8 + head] = pl;
            elr[(size_t)grow * 8 + 4 + head] = pr;
          }
        }
      }
    }
  }

#pragma unroll
  for (int ri = 0; ri < 4; ++ri) {
    int row = m0 + wr + ri * 16 + quad * 4;
#pragma unroll
    for (int ci = 0; ci < 4; ++ci) {
      int col = n0 + wc + ci * 16 + l15;
      float bv = (MODE == 2) ? bias[col] : 0.f;
#pragma unroll
      for (int r = 0; r < 4; ++r) {
        if (row + r < M) {
          float v = acc[ri][ci][r];
          if (MODE == 2) { v += bv; v = fmaxf(v, 0.f); }
          if (MODE == 1)
            ((float*)Cout)[(size_t)(row + r) * Nc + col] = v;
          else
            Cp[(size_t)(row + r) * Nc + col] = f2b(v);
        }
      }
    }
  }
}

// ---------------- GCN aggregation (16-edge batched gather) ----------------
__global__ void gcn_agg_k(const unsigned short* __restrict__ m, int ldm,
                          const int* __restrict__ row_ptr, const int* __restrict__ csr_src,
                          const float* __restrict__ ns, const float* __restrict__ nd,
                          const float* __restrict__ bias,
                          const float* __restrict__ bng, const float* __restrict__ bnb,
                          const unsigned short* __restrict__ resid, int ldr,
                          unsigned short* __restrict__ out, int ldo) {
  int node = blockIdx.x * 4 + (threadIdx.x >> 6);
  if (node >= NN) return;
  int lane = threadIdx.x & 63;
  int s = row_ptr[node], e = row_ptr[node + 1];
  int eidx = lane & 15;
  float a0 = 0, a1 = 0, a2 = 0, a3 = 0;
  for (int i0 = s; i0 < e; i0 += 16) {
    int n16 = e - i0; if (n16 > 16) n16 = 16;
    int u_mine = 0; float w_mine = 0.f;
    if (eidx < n16) {
      u_mine = csr_src[i0 + eidx];
      w_mine = ns[u_mine];
    }
    for (int e2 = 0; e2 < n16; ++e2) {
      int sl = (lane & 48) | e2;
      int u = __shfl(u_mine, sl);
      float w = __shfl(w_mine, sl);
      ushort4 v = *(const ushort4*)(m + (size_t)u * ldm + lane * 4);
      a0 += w * b2f(v.x); a1 += w * b2f(v.y); a2 += w * b2f(v.z); a3 += w * b2f(v.w);
    }
  }
  float ndv = nd[node];
  int col = lane * 4;
  float vals[4] = {a0, a1, a2, a3};
  ushort4 o;
#pragma unroll
  for (int c = 0; c < 4; ++c) {
    float v = vals[c] * ndv + bias[col + c];
    v = bng[col + c] * v * BNS + bnb[col + c];
    v = fmaxf(v, 0.f);
    if (resid) v += b2f(resid[(size_t)node * ldr + col + c]);
    ((unsigned short*)&o)[c] = f2b(v);
  }
  *(ushort4*)(out + (size_t)node * ldo + col) = o;
}

// ---------------- GAT aggregation (batched weights; 16x fewer expf) ----------------
__global__ void gat_agg_k(const unsigned short* __restrict__ f, int ldf,
                          const int* __restrict__ row_ptr, const int* __restrict__ csr_src,
                          const float* __restrict__ elr,
                          const float* __restrict__ bias,
                          const float* __restrict__ bng, const float* __restrict__ bnb,
                          const unsigned short* __restrict__ resid, int ldr,
                          unsigned short* __restrict__ out, int ldo) {
  int node = blockIdx.x * 4 + (threadIdx.x >> 6);
  if (node >= NN) return;
  int lane = threadIdx.x & 63;
  int s = row_ptr[node], e = row_ptr[node + 1];
  float4 er = *(const float4*)(elr + (size_t)node * 8 + 4);
  float m0 = -1e30f, m1 = -1e30f, m2 = -1e30f, m3 = -1e30f;
  for (int i = s + lane; i < e; i += 64) {
    int u = csr_src[i];
    float4 el = *(const float4*)(elr + (size_t)u * 8);
    float t;
    t = el.x + er.x; t = t > 0.f ? t : 0.2f * t; m0 = fmaxf(m0, t);
    t = el.y + er.y; t = t > 0.f ? t : 0.2f * t; m1 = fmaxf(m1, t);
    t = el.z + er.z; t = t > 0.f ? t : 0.2f * t; m2 = fmaxf(m2, t);
    t = el.w + er.w; t = t > 0.f ? t : 0.2f * t; m3 = fmaxf(m3, t);
  }
#pragma unroll
  for (int off = 1; off < 64; off <<= 1) {
    m0 = fmaxf(m0, __shfl_xor(m0, off));
    m1 = fmaxf(m1, __shfl_xor(m1, off));
    m2 = fmaxf(m2, __shfl_xor(m2, off));
    m3 = fmaxf(m3, __shfl_xor(m3, off));
  }
  float s0 = 0, s1 = 0, s2 = 0, s3 = 0;
  for (int i = s + lane; i < e; i += 64) {
    int u = csr_src[i];
    float4 el = *(const float4*)(elr + (size_t)u * 8);
    float t;
    t = el.x + er.x; t = t > 0.f ? t : 0.2f * t; s0 += expf(t - m0);
    t = el.y + er.y; t = t > 0.f ? t : 0.2f * t; s1 += expf(t - m1);
    t = el.z + er.z; t = t > 0.f ? t : 0.2f * t; s2 += expf(t - m2);
    t = el.w + er.w; t = t > 0.f ? t : 0.2f * t; s3 += expf(t - m3);
  }
#pragma unroll
  for (int off = 1; off < 64; off <<= 1) {
    s0 += __shfl_xor(s0, off);
    s1 += __shfl_xor(s1, off);
    s2 += __shfl_xor(s2, off);
    s3 += __shfl_xor(s3, off);
  }
  int head = lane >> 4;
  float erh = head == 0 ? er.x : head == 1 ? er.y : head == 2 ? er.z : er.w;
  float mh = head == 0 ? m0 : head == 1 ? m1 : head == 2 ? m2 : m3;
  float sh = head == 0 ? s0 : head == 1 ? s1 : head == 2 ? s2 : s3;
  float inv_sh = (sh > 0.f) ? 1.f / sh : 0.f;
  int eidx = lane & 15;
  float a0 = 0, a1 = 0, a2 = 0, a3 = 0;
  for (int i0 = s; i0 < e; i0 += 16) {
    int n16 = e - i0; if (n16 > 16) n16 = 16;
    int u_mine = 0; float w_mine = 0.f;
    if (eidx < n16) {
      u_mine = csr_src[i0 + eidx];
      float el = elr[(size_t)u_mine * 8 + head];
      float t = el + erh;
      t = t > 0.f ? t : 0.2f * t;
      w_mine = expf(t - mh) * inv_sh;
    }
    for (int e2 = 0; e2 < n16; ++e2) {
      int sl = (lane & 48) | e2;
      int u = __shfl(u_mine, sl);
      float wgt = __shfl(w_mine, sl);
      ushort4 v = *(const ushort4*)(f + (size_t)u * ldf + lane * 4);
      a0 += wgt * b2f(v.x); a1 += wgt * b2f(v.y); a2 += wgt * b2f(v.z); a3 += wgt * b2f(v.w);
    }
  }
  int col = lane * 4;
  float vals[4] = {a0, a1, a2, a3};
  ushort4 o;
#pragma unroll
  for (int c = 0; c < 4; ++c) {
    float v = vals[c] + bias[col + c];
    v = bng[col + c] * v * BNS + bnb[col + c];
    v = (v > 0.f) ? v : (expf(v) - 1.f);
    if (resid) v += b2f(resid[(size_t)node * ldr + col + c]);
    ((unsigned short*)&o)[c] = f2b(v);
  }
  *(ushort4*)(out + (size_t)node * ldo + col) = o;
}

// ---------------- per-graph node softmax ----------------
__global__ void gsoftmax_k(const float* __restrict__ att, const int* __restrict__ start,
                           float* __restrict__ alpha) {
  int g = blockIdx.x;
  int s = start[g], e = start[g + 1];
  int tid = threadIdx.x;
  __shared__ float red[256];
  __shared__ float mh[4], sh[4];
  float lm[4] = {-1e30f, -1e30f, -1e30f, -1e30f};
  for (int i = s + tid; i < e; i += 256) {
    float4 a = *(const float4*)(att + (size_t)i * 4);
    lm[0] = fmaxf(lm[0], a.x); lm[1] = fmaxf(lm[1], a.y);
    lm[2] = fmaxf(lm[2], a.z); lm[3] = fmaxf(lm[3], a.w);
  }
#pragma unroll
  for (int h = 0; h < 4; ++h) {
    red[tid] = lm[h]; __syncthreads();
    for (int off = 128; off > 0; off >>= 1) {
      if (tid < off) red[tid] = fmaxf(red[tid], red[tid + off]);
      __syncthreads();
    }
    if (tid == 0) mh[h] = red[0];
    __syncthreads();
  }
  float ls[4] = {0, 0, 0, 0};
  for (int i = s + tid; i < e; i += 256) {
    float4 a = *(const float4*)(att + (size_t)i * 4);
    ls[0] += expf(a.x - mh[0]); ls[1] += expf(a.y - mh[1]);
    ls[2] += expf(a.z - mh[2]); ls[3] += expf(a.w - mh[3]);
  }
#pragma unroll
  for (int h = 0; h < 4; ++h) {
    red[tid] = ls[h]; __syncthreads();
    for (int off = 128; off > 0; off >>= 1) {
      if (tid < off) red[tid] += red[tid + off];
      __syncthreads();
    }
    if (tid == 0) sh[h] = red[0];
    __syncthreads();
  }
  for (int i = s + tid; i < e; i += 256) {
    float4 a = *(const float4*)(att + (size_t)i * 4);
    float4 o;
    o.x = expf(a.x - mh[0]) / sh[0];
    o.y = expf(a.y - mh[1]) / sh[1];
    o.z = expf(a.z - mh[2]) / sh[2];
    o.w = expf(a.w - mh[3]) / sh[3];
    *(float4*)(alpha + (size_t)i * 4) = o;
  }
}

// ---------------- LayerNorms (all bf16 in/out) ----------------
__global__ void ln1_k(const unsigned short* __restrict__ mo, const unsigned short* __restrict__ x,
                      const float* __restrict__ g, const float* __restrict__ b,
                      unsigned short* __restrict__ x1) {
  int node = blockIdx.x * 4 + (threadIdx.x >> 6);
  if (node >= NN) return;
  int lane = threadIdx.x & 63;
  int c = lane * 4;
  ushort4 a = *(const ushort4*)(mo + (size_t)node * HIDDEN + c);
  ushort4 xx = *(const ushort4*)(x + (size_t)node * HIDDEN + c);
  float v0 = b2f(a.x) + b2f(xx.x), v1 = b2f(a.y) + b2f(xx.y);
  float v2 = b2f(a.z) + b2f(xx.z), v3 = b2f(a.w) + b2f(xx.w);
  float sm = v0 + v1 + v2 + v3;
#pragma unroll
  for (int off = 1; off < 64; off <<= 1) sm += __shfl_xor(sm, off);
  float mu = sm * (1.f / 256.f);
  float d0 = v0 - mu, d1 = v1 - mu, d2 = v2 - mu, d3 = v3 - mu;
  float sq = d0 * d0 + d1 * d1 + d2 * d2 + d3 * d3;
#pragma unroll
  for (int off = 1; off < 64; off <<= 1) sq += __shfl_xor(sq, off);
  float inv = rsqrtf(sq * (1.f / 256.f) + LN_EPS);
  ushort4 ob;
  ob.x = f2b(g[c + 0] * d0 * inv + b[c + 0]);
  ob.y = f2b(g[c + 1] * d1 * inv + b[c + 1]);
  ob.z = f2b(g[c + 2] * d2 * inv + b[c + 2]);
  ob.w = f2b(g[c + 3] * d3 * inv + b[c + 3]);
  *(ushort4*)(x1 + (size_t)node * HIDDEN + c) = ob;
}

__global__ void ln2_k(const unsigned short* __restrict__ ff2o, const float* __restrict__ ffb2,
                      const unsigned short* __restrict__ x1,
                      const float* __restrict__ g, const float* __restrict__ b,
                      unsigned short* __restrict__ x2) {
  int node = blockIdx.x * 4 + (threadIdx.x >> 6);
  if (node >= NN) return;
  int lane = threadIdx.x & 63;
  int c = lane * 4;
  ushort4 a = *(const ushort4*)(ff2o + (size_t)node * HIDDEN + c);
  ushort4 xx = *(const ushort4*)(x1 + (size_t)node * HIDDEN + c);
  float v0 = b2f(a.x) + ffb2[c + 0] + b2f(xx.x), v1 = b2f(a.y) + ffb2[c + 1] + b2f(xx.y);
  float v2 = b2f(a.z) + ffb2[c + 2] + b2f(xx.z), v3 = b2f(a.w) + ffb2[c + 3] + b2f(xx.w);
  float sm = v0 + v1 + v2 + v3;
#pragma unroll
  for (int off = 1; off < 64; off <<= 1) sm += __shfl_xor(sm, off);
  float mu = sm * (1.f / 256.f);
  float d0 = v0 - mu, d1 = v1 - mu, d2 = v2 - mu, d3 = v3 - mu;
  float sq = d0 * d0 + d1 * d1 + d2 * d2 + d3 * d3;
#pragma unroll
  for (int off = 1; off < 64; off <<= 1) sq += __shfl_xor(sq, off);
  float inv = rsqrtf(sq * (1.f / 256.f) + LN_EPS);
  ushort4 ob;
  ob.x = f2b(g[c + 0] * d0 * inv + b[c + 0]);
  ob.y = f2b(g[c + 1] * d1 * inv + b[c + 1]);
  ob.z = f2b(g[c + 2] * d2 * inv + b[c + 2]);
  ob.w = f2b(g[c + 3] * d3 * inv + b[c + 3]);
  *(ushort4*)(x2 + (size_t)node * HIDDEN + c) = ob;
}

// ---------------- readout (output 0) ----------------
__global__ void readout_k(const unsigned short* __restrict__ x2, const int* __restrict__ start,
                          float* __restrict__ out0) {
  int g = blockIdx.x;
  int c = threadIdx.x;
  float acc = 0.f;
  for (int i = start[g]; i < start[g + 1]; ++i) acc += b2f(x2[(size_t)i * HIDDEN + c]);
  out0[(size_t)g * HIDDEN + c] = acc;
}

// ---------------- workspace layout (bytes) ----------------
static const size_t OFF_BUFA   = 0;
static const size_t OFF_C01    = 128000000;
static const size_t OFF_HG0    = 179200000;
static const size_t OFF_HA0    = 204800000;
static const size_t OFF_M1     = 230400000;
static const size_t OFF_F1     = 256000000;
static const size_t OFF_XCAT   = 281600000;
static const size_t OFF_XB     = 358400000;
static const size_t OFF_MO     = 384000000;
static const size_t OFF_X1     = 409600000;
static const size_t OFF_ATT    = 435200000;
static const size_t OFF_ALPHA  = OFF_ATT + 800000;
static const size_t OFF_ELR0   = OFF_ALPHA + 800000;
static const size_t OFF_ELR1   = OFF_ELR0 + 1600000;
static const size_t OFF_START  = OFF_ELR1 + 1600000;
// deg_out, deg_in, fill contiguous -> single memset
static const size_t OFF_DEGO   = OFF_START + 1024;
static const size_t OFF_DEGI   = OFF_DEGO + 200704;
static const size_t OFF_FILL   = OFF_DEGI + 200704;
static const size_t OFF_NS     = OFF_FILL + 200704;
static const size_t OFF_ND     = OFF_NS + 200704;
static const size_t OFF_ROWP   = OFF_ND + 200704;
static const size_t OFF_BSUM   = OFF_ROWP + 200704;
static const size_t OFF_BOFF   = OFF_BSUM + 1024;
static const size_t OFF_CSRS   = OFF_BOFF + 1024;
static const size_t OFF_W01T   = OFF_CSRS + 3200000;
static const size_t OFF_W1T    = OFF_W01T + 1310720;
static const size_t OFF_W1GT   = OFF_W1T + 131072;
static const size_t OFF_GATEWT = OFF_W1GT + 131072;
static const size_t OFF_WMVT   = OFF_GATEWT + 262144;
static const size_t OFF_CTWT   = OFF_WMVT + 1048576;
static const size_t OFF_FFW1T  = OFF_CTWT + 524288;
static const size_t OFF_FFW2T  = OFF_FFW1T + 262144;
static const size_t WS_NEED    = OFF_FFW2T + 262144;

extern "C" void kernel_launch(void* const* d_in, const int* in_sizes, int n_in,
                              void* d_out, int out_size, void* d_ws, size_t ws_size,
                              hipStream_t stream) {
  if (ws_size < WS_NEED) return;

  const float* h       = (const float*)d_in[0];
  const float* gcn_w0  = (const float*)d_in[1];
  const float* gcn_b0  = (const float*)d_in[2];
  const float* gcn_w1  = (const float*)d_in[3];
  const float* gcn_b1  = (const float*)d_in[4];
  const float* bn_gcn0_g = (const float*)d_in[5];
  const float* bn_gcn0_b = (const float*)d_in[6];
  const float* bn_gcn1_g = (const float*)d_in[7];
  const float* bn_gcn1_b = (const float*)d_in[8];
  const float* gat_w0  = (const float*)d_in[9];
  const float* gat_al0 = (const float*)d_in[10];
  const float* gat_ar0 = (const float*)d_in[11];
  const float* gat_bias0 = (const float*)d_in[12];
  const float* gat_w1  = (const float*)d_in[13];
  const float* gat_al1 = (const float*)d_in[14];
  const float* gat_ar1 = (const float*)d_in[15];
  const float* gat_bias1 = (const float*)d_in[16];
  const float* bn_gat0_g = (const float*)d_in[17];
  const float* bn_gat0_b = (const float*)d_in[18];
  const float* bn_gat1_g = (const float*)d_in[19];
  const float* bn_gat1_b = (const float*)d_in[20];
  const float* gate_w  = (const float*)d_in[21];
  const float* gate_b  = (const float*)d_in[22];
  const float* qw      = (const float*)d_in[23];
  const float* kw      = (const float*)d_in[24];
  const float* vw      = (const float*)d_in[25];
  const float* ct_w    = (const float*)d_in[26];
  const float* ff_w1   = (const float*)d_in[27];
  const float* ff_b1   = (const float*)d_in[28];
  const float* ff_w2   = (const float*)d_in[29];
  const float* ff_b2   = (const float*)d_in[30];
  const float* ln_g    = (const float*)d_in[31];
  const float* ln_b    = (const float*)d_in[32];
  const int* srcv = (const int*)d_in[33];
  const int* dstv = (const int*)d_in[34];
  const int* gid  = (const int*)d_in[35];

  char* ws = (char*)d_ws;
  unsigned short* h_bf = (unsigned short*)(ws + OFF_BUFA);
  unsigned short* ff1o = (unsigned short*)(ws + OFF_BUFA);
  unsigned short* ff2o = (unsigned short*)(ws + OFF_BUFA + 51200000);
  unsigned short* x2   = (unsigned short*)(ws + OFF_BUFA + 76800000);
  unsigned short* c01  = (unsigned short*)(ws + OFF_C01);
  unsigned short* hg0  = (unsigned short*)(ws + OFF_HG0);
  unsigned short* ha0  = (unsigned short*)(ws + OFF_HA0);
  unsigned short* m1   = (unsigned short*)(ws + OFF_M1);
  unsigned short* f1   = (unsigned short*)(ws + OFF_F1);
  unsigned short* xcat = (unsigned short*)(ws + OFF_XCAT);
  unsigned short* xb   = (unsigned short*)(ws + OFF_XB);
  unsigned short* mo   = (unsigned short*)(ws + OFF_MO);
  unsigned short* x1   = (unsigned short*)(ws + OFF_X1);
  float* att           = (float*)(ws + OFF_ATT);
  float* alpha         = (float*)(ws + OFF_ALPHA);
  float* elr0          = (float*)(ws + OFF_ELR0);
  float* elr1          = (float*)(ws + OFF_ELR1);
  int* start   = (int*)(ws + OFF_START);
  int* deg_out = (int*)(ws + OFF_DEGO);
  int* deg_in  = (int*)(ws + OFF_DEGI);
  int* fill    = (int*)(ws + OFF_FILL);
  float* ns    = (float*)(ws + OFF_NS);
  float* nd    = (float*)(ws + OFF_ND);
  int* row_ptr = (int*)(ws + OFF_ROWP);
  int* bsum    = (int*)(ws + OFF_BSUM);
  int* boff    = (int*)(ws + OFF_BOFF);
  int* csr_src = (int*)(ws + OFF_CSRS);
  unsigned short* w01t   = (unsigned short*)(ws + OFF_W01T);
  unsigned short* w1t    = (unsigned short*)(ws + OFF_W1T);
  unsigned short* w1gt   = (unsigned short*)(ws + OFF_W1GT);
  unsigned short* gatewt = (unsigned short*)(ws + OFF_GATEWT);
  unsigned short* wmvt   = (unsigned short*)(ws + OFF_WMVT);
  unsigned short* w2t    = (unsigned short*)(ws + OFF_CTWT);
  unsigned short* ffw1t  = (unsigned short*)(ws + OFF_FFW1T);
  unsigned short* ffw2t  = (unsigned short*)(ws + OFF_FFW2T);

  float* out0 = (float*)d_out;            // readout [128,256]
  float* out1 = out0 + NG * HIDDEN;       // init_avg_h [128,1280]

  hipMemsetAsync(deg_out, 0, 3 * 200704, stream);   // deg_out + deg_in + fill (contiguous)
  hipMemsetAsync(out1, 0, NG * DIN * 4, stream);
  hipMemsetAsync(att, 0, NN * 4 * 4, stream);

  // merged weight prep (1 dispatch)
  prep_all_k<<<6656, 256, 0, stream>>>(gcn_w0, gat_w0, gcn_w1, gat_w1, gate_w, ff_w1, ff_w2,
                                       qw, kw, vw, ct_w,
                                       w01t, w1t, w1gt, gatewt, ffw1t, ffw2t, wmvt, w2t);

  // graph structure (merged)
  bounds_deg_k<<<(NE + 255) / 256, 256, 0, stream>>>(gid, start, srcv, dstv, deg_out, deg_in);
  const int NB_SCAN = (NN + 255) / 256;
  scan_local_k<<<NB_SCAN, 256, 0, stream>>>(deg_in, deg_out, row_ptr, bsum, ns, nd);
  scan_bsum_k<<<1, 256, 0, stream>>>(bsum, boff, NB_SCAN, row_ptr);
  scan_add_k<<<NB_SCAN, 256, 0, stream>>>(row_ptr, boff);
  fill_csr_k<<<(NE + 255) / 256, 256, 0, stream>>>(srcv, dstv, row_ptr, fill, csr_src, NE);

  // fused h->bf16 + per-graph sums, then divide
  cvt_avg_k<<<NN / 50, 320, 0, stream>>>(h, gid, h_bf, out1);
  div_avg_k<<<(NG * DIN + 255) / 256, 256, 0, stream>>>(start, out1);

  const int MB = (NN + 127) / 128;
  // GEMM1: h @ [gcn_w0 | gat_w0] -> c01 [N,512] with fused elr0 (gat cols >=256)
  gemm_bf16<8><<<dim3(4, MB), 256, 0, stream>>>(h_bf, w01t, c01, nullptr, NN, 1280, 512,
                                                nullptr, nullptr, nullptr,
                                                gat_al0, gat_ar0, elr0, 256);
  gcn_agg_k<<<NN / 4, 256, 0, stream>>>(c01, 512, row_ptr, csr_src, ns, nd,
                                        gcn_b0, bn_gcn0_g, bn_gcn0_b, nullptr, 0, hg0, 256);
  gat_agg_k<<<NN / 4, 256, 0, stream>>>(c01 + 256, 512, row_ptr, csr_src, elr0,
                                        gat_bias0, bn_gat0_g, bn_gat0_b, nullptr, 0, ha0, 256);
  // layer 1: merged m1 (z=0) and f1+elr1 (z=1) GEMMs
  gemm_bf16<8><<<dim3(2, MB, 2), 256, 0, stream>>>(hg0, w1t, m1, nullptr, NN, 256, 256,
                                                   nullptr, nullptr, nullptr,
                                                   gat_al1, gat_ar1, elr1, 0);
  gcn_agg_k<<<NN / 4, 256, 0, stream>>>(m1, 256, row_ptr, csr_src, ns, nd,
                                        gcn_b1, bn_gcn1_g, bn_gcn1_b, hg0, 256, xcat, 512);
  gat_agg_k<<<NN / 4, 256, 0, stream>>>(f1, 256, row_ptr, csr_src, elr1,
                                        gat_bias1, bn_gat1_g, bn_gat1_b, ha0, 256, xcat + 256, 512);
  // gate GEMM with fused sigmoid-blend epilogue -> xb
  gemm_bf16<7><<<dim3(2, MB), 256, 0, stream>>>(xcat, gatewt, xb, gate_b, NN, 512, 256,
                                                xcat, nullptr, nullptr,
                                                nullptr, nullptr, nullptr, 0);
  // transformer: att = x^T M_h x via att epilogue (M-part only; V folded into W2)
  gemm_bf16<4><<<dim3(8, MB), 256, 0, stream>>>(xb, wmvt, nullptr, nullptr, NN, 256, 1024,
                                                xb, att, nullptr,
                                                nullptr, nullptr, nullptr, 0);
  gsoftmax_k<<<NG, 256, 0, stream>>>(att, start, alpha);
  // mo = (alpha-scaled xb, head-major K=1024) @ W2cat
  gemm_bf16<6><<<dim3(2, MB), 256, 0, stream>>>(xb, w2t, mo, nullptr, NN, 1024, 256,
                                                nullptr, nullptr, alpha,
                                                nullptr, nullptr, nullptr, 0);
  ln1_k<<<NN / 4, 256, 0, stream>>>(mo, xb, ln_g, ln_b, x1);
  gemm_bf16<2><<<dim3(4, MB), 256, 0, stream>>>(x1, ffw1t, ff1o, ff_b1, NN, 256, 512,
                                                nullptr, nullptr, nullptr,
                                                nullptr, nullptr, nullptr, 0);
  gemm_bf16<0><<<dim3(2, MB), 256, 0, stream>>>(ff1o, ffw2t, ff2o, nullptr, NN, 512, 256,
                                                nullptr, nullptr, nullptr,
                                                nullptr, nullptr, nullptr, 0);
  ln2_k<<<NN / 4, 256, 0, stream>>>(ff2o, ff_b2, x1, ln_g, ln_b, x2);
  readout_k<<<NG, 256, 0, stream>>>(x2, start, out0);
}

// Round 6
// 1539.223 us; speedup vs baseline: 1.1886x; 1.0237x over previous
//
#include <hip/hip_runtime.h>

#define NN 50000
#define NE 800000
#define NG 128
#define DIN 1280
#define HIDDEN 256
#define BNS 0.9999950000374997f
#define ATT_SCALE 0.027950849718747373f
#define LN_EPS 1e-5f

typedef __attribute__((ext_vector_type(8))) short short8;
typedef __attribute__((ext_vector_type(4))) float floatx4;

__device__ __forceinline__ float b2f(unsigned short u) {
  return __uint_as_float(((unsigned int)u) << 16);
}
__device__ __forceinline__ unsigned short f2b(float f) {
  unsigned int x = __float_as_uint(f);
  x += 0x7fffu + ((x >> 16) & 1u);
  return (unsigned short)(x >> 16);
}

// ---------------- merged weight prep (one dispatch) ----------------
__device__ __forceinline__ void tr_dev(const float* __restrict__ src,
                                       unsigned short* __restrict__ dst,
                                       int K, int Nc, int bi) {
  int idx = bi * 256 + threadIdx.x;
  if (idx >= K * Nc) return;
  int n = idx / K, k = idx % K;
  dst[idx] = f2b(src[(size_t)k * Nc + n]);
}

__global__ void prep_all_k(const float* __restrict__ gcn_w0, const float* __restrict__ gat_w0,
                           const float* __restrict__ gcn_w1, const float* __restrict__ gat_w1,
                           const float* __restrict__ gate_w, const float* __restrict__ ff_w1,
                           const float* __restrict__ ff_w2, const float* __restrict__ qw,
                           const float* __restrict__ kw, const float* __restrict__ vw,
                           const float* __restrict__ ctw,
                           unsigned short* __restrict__ w01t, unsigned short* __restrict__ w1t,
                           unsigned short* __restrict__ w1gt, unsigned short* __restrict__ gatewt,
                           unsigned short* __restrict__ ffw1t, unsigned short* __restrict__ ffw2t,
                           unsigned short* __restrict__ wmvt, unsigned short* __restrict__ w2t) {
  int b = blockIdx.x;
  if (b < 1280) { tr_dev(gcn_w0, w01t, 1280, 256, b); return; }
  if (b < 2560) { tr_dev(gat_w0, w01t + 256 * 1280, 1280, 256, b - 1280); return; }
  if (b < 2816) { tr_dev(gcn_w1, w1t, 256, 256, b - 2560); return; }
  if (b < 3072) { tr_dev(gat_w1, w1gt, 256, 256, b - 2816); return; }
  if (b < 3584) { tr_dev(gate_w, gatewt, 512, 256, b - 3072); return; }
  if (b < 4096) { tr_dev(ff_w1, ffw1t, 256, 512, b - 3584); return; }
  if (b < 4608) { tr_dev(ff_w2, ffw2t, 512, 256, b - 4096); return; }
  if (b < 5632) {
    int col = b - 4608;
    int d = threadIdx.x;
    int hh = col >> 8, dp = col & 255;
    const float* qr = qw + ((size_t)hh * 256 + d) * 256;
    const float* kr = kw + ((size_t)hh * 256 + dp) * 256;
    float s = 0.f;
    for (int e = 0; e < 256; e += 4) {
      float4 a = *(const float4*)(qr + e);
      float4 bb = *(const float4*)(kr + e);
      s += a.x * bb.x + a.y * bb.y + a.z * bb.z + a.w * bb.w;
    }
    wmvt[(size_t)col * 256 + d] = f2b(s);
    return;
  }
  {
    int bb = b - 5632;
    int c = threadIdx.x;
    int hh = bb >> 8, d = bb & 255;
    const float* vr = vw + ((size_t)hh * 256 + d) * 256;
    float s = 0.f;
    for (int e = 0; e < 256; ++e)
      s += vr[e] * ctw[(size_t)(hh * 256 + e) * 256 + c];
    w2t[(size_t)c * 1024 + bb] = f2b(s);
  }
}

// ---------------- fused h->bf16 conversion + per-graph sum (float4) ----------------
__global__ void cvt_avg_k(const float* __restrict__ h, const int* __restrict__ gid,
                          unsigned short* __restrict__ h_bf, float* __restrict__ out1) {
  int row0 = blockIdx.x * 50;
  int tid = threadIdx.x;     // 0..319
  float4 acc = {0.f, 0.f, 0.f, 0.f};
  int cur_g = gid[row0];
  int c4 = tid * 4;
  for (int r = 0; r < 50; ++r) {
    int row = row0 + r;
    int g = gid[row];
    if (g != cur_g) {
      atomicAdd(&out1[(size_t)cur_g * DIN + c4 + 0], acc.x);
      atomicAdd(&out1[(size_t)cur_g * DIN + c4 + 1], acc.y);
      atomicAdd(&out1[(size_t)cur_g * DIN + c4 + 2], acc.z);
      atomicAdd(&out1[(size_t)cur_g * DIN + c4 + 3], acc.w);
      acc = {0.f, 0.f, 0.f, 0.f};
      cur_g = g;
    }
    float4 v = *(const float4*)(h + (size_t)row * DIN + c4);
    acc.x += v.x; acc.y += v.y; acc.z += v.z; acc.w += v.w;
    ushort4 o;
    o.x = f2b(v.x); o.y = f2b(v.y); o.z = f2b(v.z); o.w = f2b(v.w);
    *(ushort4*)(h_bf + (size_t)row * DIN + c4) = o;
  }
  atomicAdd(&out1[(size_t)cur_g * DIN + c4 + 0], acc.x);
  atomicAdd(&out1[(size_t)cur_g * DIN + c4 + 1], acc.y);
  atomicAdd(&out1[(size_t)cur_g * DIN + c4 + 2], acc.z);
  atomicAdd(&out1[(size_t)cur_g * DIN + c4 + 3], acc.w);
}

__global__ void div_avg_k(const int* __restrict__ start, float* __restrict__ out1) {
  int idx = blockIdx.x * 256 + threadIdx.x;
  if (idx >= NG * DIN) return;
  int g = idx / DIN;
  float cnt = (float)(start[g + 1] - start[g]);
  if (cnt < 1.f) cnt = 1.f;
  out1[idx] /= cnt;
}

// ---------------- graph structure (merged) ----------------
__global__ void bounds_deg_k(const int* __restrict__ gid, int* __restrict__ start,
                             const int* __restrict__ src, const int* __restrict__ dst,
                             int* __restrict__ deg_out, int* __restrict__ deg_in) {
  int i = blockIdx.x * 256 + threadIdx.x;
  if (i < NN) {
    int g = gid[i];
    if (i == 0) {
      for (int gg = 0; gg <= g; ++gg) start[gg] = 0;
    } else {
      int gp = gid[i - 1];
      for (int gg = gp + 1; gg <= g; ++gg) start[gg] = i;
    }
    if (i == NN - 1) {
      for (int gg = g + 1; gg <= NG; ++gg) start[gg] = NN;
    }
  }
  if (i < NE) {
    atomicAdd(&deg_out[src[i]], 1);
    atomicAdd(&deg_in[dst[i]], 1);
  }
}

// local scan of deg_in + fused ns/nd computation
__global__ void scan_local_k(const int* __restrict__ deg_in, const int* __restrict__ deg_out,
                             int* __restrict__ row_ptr, int* __restrict__ bsum,
                             float* __restrict__ ns, float* __restrict__ nd) {
  __shared__ int buf[256];
  int b = blockIdx.x, t = threadIdx.x;
  int i = b * 256 + t;
  int v = (i < NN) ? deg_in[i] : 0;
  buf[t] = v;
  __syncthreads();
  for (int off = 1; off < 256; off <<= 1) {
    int tv = (t >= off) ? buf[t - off] : 0;
    __syncthreads();
    buf[t] += tv;
    __syncthreads();
  }
  if (i < NN) {
    row_ptr[i] = buf[t] - v;
    int a = deg_out[i]; if (a < 1) a = 1;
    int bb = v;         if (bb < 1) bb = 1;
    ns[i] = rsqrtf((float)a);
    nd[i] = rsqrtf((float)bb);
  }
  if (t == 255) bsum[b] = buf[255];
}

__global__ void scan_bsum_k(int* __restrict__ bsum, int* __restrict__ boff, int nb,
                            int* __restrict__ row_ptr) {
  __shared__ int buf[256];
  int t = threadIdx.x;
  int v = (t < nb) ? bsum[t] : 0;
  buf[t] = v;
  __syncthreads();
  for (int off = 1; off < 256; off <<= 1) {
    int tv = (t >= off) ? buf[t - off] : 0;
    __syncthreads();
    buf[t] += tv;
    __syncthreads();
  }
  if (t < nb) boff[t] = buf[t] - v;
  if (t == 0) row_ptr[NN] = NE;
}

__global__ void scan_add_k(int* __restrict__ row_ptr, const int* __restrict__ boff) {
  int i = blockIdx.x * 256 + threadIdx.x;
  if (i >= NN) return;
  row_ptr[i] += boff[blockIdx.x];
}

__global__ void fill_csr_k(const int* __restrict__ src, const int* __restrict__ dst,
                           const int* __restrict__ row_ptr, int* __restrict__ fill,
                           int* __restrict__ csr_src, int e) {
  int i = blockIdx.x * 256 + threadIdx.x;
  if (i >= e) return;
  int d = dst[i];
  int pos = row_ptr[d] + atomicAdd(&fill[d], 1);
  csr_src[pos] = src[i];
}

// ---------------- bf16 MFMA GEMM ----------------
// C[M,Nc] = A[M,K] * Bt[Nc,K]   (both bf16)
// LDS cell(r,kb) = r*8 + (kb ^ (r&7)); double-buffered (2x32KB).
// Bijective XCD swizzle (m204): consecutive logical blocks (sharing A-tile)
// land on one XCD's L2 -> A/B re-reads become L2 hits.
// MODE 0: bf16 out; 1: fp32 out; 2: +bias relu bf16 out;
// MODE 4: att epilogue (quadratic form row-dot with xtile), no C store
// MODE 6: A synthesized as xb[gm, k&255] * ascale[gm*4 + (k>>8)] (reg-staged, single-buffer)
// MODE 7: gate epilogue: xb = sigmoid(acc+bias)*xcat[:,c] + (1-s)*xcat[:,256+c]
// MODE 8: bf16 out + fused el/er epilogue for gat cols (>= ecol0).
//         If gridDim.z==2 (layer1): z=0 -> (hg0,w1t) -> mf cols 0-255, no elr;
//         z=1 -> (ha0,w1gt) -> mf cols 256-511 + elr.
template <int MODE>
__global__ __launch_bounds__(256, 2) void gemm_bf16(const unsigned short* __restrict__ A,
                                                    const unsigned short* __restrict__ Bt,
                                                    void* __restrict__ Cout,
                                                    const float* __restrict__ bias,
                                                    int M, int K, int Nc,
                                                    const unsigned short* __restrict__ xtile,
                                                    float* __restrict__ attp,
                                                    const float* __restrict__ ascale,
                                                    const float* __restrict__ al,
                                                    const float* __restrict__ ar,
                                                    float* __restrict__ elr,
                                                    int ecol0) {
  __shared__ unsigned short sbuf[32768];
  const int tid = threadIdx.x;
  // m204 bijective XCD swizzle on (x,y)
  const int gx = gridDim.x;
  const int nwg = gx * gridDim.y;
  const int orig = blockIdx.y * gx + blockIdx.x;
  const int xcd = orig & 7;
  const int q = nwg >> 3, r = nwg & 7;
  const int wg = (xcd < r ? xcd * (q + 1) : r * (q + 1) + (xcd - r) * q) + (orig >> 3);
  const int n0 = (wg % gx) * 128;
  const int m0 = (wg / gx) * 128;
  const int w = tid >> 6;
  const int lane = tid & 63;
  const int wr = (w >> 1) * 64;
  const int wc = (w & 1) * 64;
  const int quad = lane >> 4;
  const int l15 = lane & 15;
  const int js = tid & 7;
  const int mbase = tid >> 3;
  const int wbase = w * 64;

  bool do_elr = (MODE == 8);
  int cz = 0;
  const unsigned short* Ap = A;
  const unsigned short* Bp = Bt;
  unsigned short* Cp = (unsigned short*)Cout;
  if (MODE == 8 && gridDim.z == 2) {
    if (blockIdx.z == 0) {
      do_elr = false;
    } else {
      Ap += 12800000;   // ha0 - hg0 (ushorts)
      Bp += 65536;      // w1gt - w1t
      cz = 256;         // write into cols 256-511 of mf
    }
  }

  floatx4 acc[4][4];
#pragma unroll
  for (int i = 0; i < 4; ++i)
#pragma unroll
    for (int j = 0; j < 4; ++j) acc[i][j] = (floatx4)0.0f;

  if constexpr (MODE == 6) {
    unsigned short* lA = sbuf;
    unsigned short* lB = sbuf + 8192;
    for (int k0 = 0; k0 < K; k0 += 64) {
      __syncthreads();
#pragma unroll
      for (int it = 0; it < 4; ++it) {
        int m = it * 32 + mbase;
        int gm = m0 + m;
        if (gm >= M) gm = M - 1;
        uint4 va = *(const uint4*)(Ap + (size_t)gm * 256 + (k0 & 255) + js * 8);
        float s = ascale[(size_t)gm * 4 + (k0 >> 8)];
        unsigned short* pp = (unsigned short*)&va;
#pragma unroll
        for (int c = 0; c < 8; ++c) pp[c] = f2b(b2f(pp[c]) * s);
        *(uint4*)(lA + (size_t)(m * 8 + (js ^ (m & 7))) * 8) = va;
      }
#pragma unroll
      for (int it = 0; it < 4; ++it) {
        int c = it * 256 + wbase + lane;
        int m = c >> 3, g = c & 7;
        int gn = n0 + m;
        const unsigned short* gp = Bp + (size_t)gn * K + k0 + (g ^ (m & 7)) * 8;
        __builtin_amdgcn_global_load_lds(
            (const __attribute__((address_space(1))) unsigned int*)gp,
            (__attribute__((address_space(3))) unsigned int*)(lB + (size_t)(it * 256 + wbase) * 8),
            16, 0, 0);
      }
      __syncthreads();
#pragma unroll
      for (int ks = 0; ks < 2; ++ks) {
        int kb = ks * 4 + quad;
        short8 af[4], bfr[4];
#pragma unroll
        for (int ri = 0; ri < 4; ++ri) {
          int rr = wr + ri * 16 + l15;
          af[ri] = *(const short8*)(lA + (size_t)(rr * 8 + (kb ^ (rr & 7))) * 8);
        }
#pragma unroll
        for (int ci = 0; ci < 4; ++ci) {
          int c = wc + ci * 16 + l15;
          bfr[ci] = *(const short8*)(lB + (size_t)(c * 8 + (kb ^ (c & 7))) * 8);
        }
#pragma unroll
        for (int ri = 0; ri < 4; ++ri)
#pragma unroll
          for (int ci = 0; ci < 4; ++ci)
            acc[ri][ci] = __builtin_amdgcn_mfma_f32_16x16x32_bf16(af[ri], bfr[ci], acc[ri][ci], 0, 0, 0);
      }
    }
    __syncthreads();
  } else {
    const int nt = K >> 6;
    auto stage = [&](int b, int k0) {
      unsigned short* lA = sbuf + b * 16384;
      unsigned short* lB = lA + 8192;
#pragma unroll
      for (int it = 0; it < 4; ++it) {
        int c = it * 256 + wbase + lane;
        int m = c >> 3, g = c & 7;
        int gm = m0 + m;
        if (gm >= M) gm = M - 1;
        const unsigned short* gp = Ap + (size_t)gm * K + k0 + (g ^ (m & 7)) * 8;
        __builtin_amdgcn_global_load_lds(
            (const __attribute__((address_space(1))) unsigned int*)gp,
            (__attribute__((address_space(3))) unsigned int*)(lA + (size_t)(it * 256 + wbase) * 8),
            16, 0, 0);
      }
#pragma unroll
      for (int it = 0; it < 4; ++it) {
        int c = it * 256 + wbase + lane;
        int m = c >> 3, g = c & 7;
        int gn = n0 + m;
        const unsigned short* gp = Bp + (size_t)gn * K + k0 + (g ^ (m & 7)) * 8;
        __builtin_amdgcn_global_load_lds(
            (const __attribute__((address_space(1))) unsigned int*)gp,
            (__attribute__((address_space(3))) unsigned int*)(lB + (size_t)(it * 256 + wbase) * 8),
            16, 0, 0);
      }
    };
    stage(0, 0);
    __syncthreads();
    for (int t = 0; t < nt; ++t) {
      int cur = t & 1;
      if (t + 1 < nt) stage(cur ^ 1, (t + 1) * 64);
      unsigned short* lA = sbuf + cur * 16384;
      unsigned short* lB = lA + 8192;
#pragma unroll
      for (int ks = 0; ks < 2; ++ks) {
        int kb = ks * 4 + quad;
        short8 af[4], bfr[4];
#pragma unroll
        for (int ri = 0; ri < 4; ++ri) {
          int rr = wr + ri * 16 + l15;
          af[ri] = *(const short8*)(lA + (size_t)(rr * 8 + (kb ^ (rr & 7))) * 8);
        }
#pragma unroll
        for (int ci = 0; ci < 4; ++ci) {
          int c = wc + ci * 16 + l15;
          bfr[ci] = *(const short8*)(lB + (size_t)(c * 8 + (kb ^ (c & 7))) * 8);
        }
#pragma unroll
        for (int ri = 0; ri < 4; ++ri)
#pragma unroll
          for (int ci = 0; ci < 4; ++ci)
            acc[ri][ci] = __builtin_amdgcn_mfma_f32_16x16x32_bf16(af[ri], bfr[ci], acc[ri][ci], 0, 0, 0);
      }
      __syncthreads();
    }
  }

  if (MODE == 4) {
    int cb = n0 & 255;
#pragma unroll
    for (int it2 = 0; it2 < 8; ++it2) {
      int linear = it2 * 256 + tid;
      int rr = linear >> 4;
      int c8 = (linear & 15) * 8;
      int gr = m0 + rr;
      if (gr >= M) gr = M - 1;
      *(uint4*)(sbuf + rr * 128 + c8) = *(const uint4*)(xtile + (size_t)gr * 256 + cb + c8);
    }
    __syncthreads();
    int head = n0 >> 8;
#pragma unroll
    for (int ri = 0; ri < 4; ++ri) {
      int lrow = wr + ri * 16 + quad * 4;
#pragma unroll
      for (int r2 = 0; r2 < 4; ++r2) {
        float p = 0.f;
#pragma unroll
        for (int ci = 0; ci < 4; ++ci)
          p += acc[ri][ci][r2] * b2f(sbuf[(lrow + r2) * 128 + wc + ci * 16 + l15]);
        p += __shfl_xor(p, 1);
        p += __shfl_xor(p, 2);
        p += __shfl_xor(p, 4);
        p += __shfl_xor(p, 8);
        if (l15 == 0) {
          int grow = m0 + lrow + r2;
          if (grow < M) atomicAdd(&attp[(size_t)grow * 4 + head], p * ATT_SCALE);
        }
      }
    }
    return;
  }

  if (MODE == 7) {
#pragma unroll
    for (int ri = 0; ri < 4; ++ri) {
      int row = m0 + wr + ri * 16 + quad * 4;
#pragma unroll
      for (int ci = 0; ci < 4; ++ci) {
        int col = n0 + wc + ci * 16 + l15;
        float bv = bias[col];
#pragma unroll
        for (int r2 = 0; r2 < 4; ++r2) {
          if (row + r2 < M) {
            float g = 1.f / (1.f + expf(-(acc[ri][ci][r2] + bv)));
            float hg = b2f(xtile[(size_t)(row + r2) * 512 + col]);
            float ha = b2f(xtile[(size_t)(row + r2) * 512 + 256 + col]);
            Cp[(size_t)(row + r2) * Nc + col] = f2b(g * hg + (1.f - g) * ha);
          }
        }
      }
    }
    return;
  }

  if (MODE == 8 && do_elr && n0 >= ecol0) {
    int head = (n0 - ecol0 + wc) >> 6;
#pragma unroll
    for (int ri = 0; ri < 4; ++ri) {
      int lrow = wr + ri * 16 + quad * 4;
#pragma unroll
      for (int r2 = 0; r2 < 4; ++r2) {
        float pl = 0.f, pr = 0.f;
#pragma unroll
        for (int ci = 0; ci < 4; ++ci) {
          float fv = acc[ri][ci][r2];
          pl += fv * al[head * 64 + ci * 16 + l15];
          pr += fv * ar[head * 64 + ci * 16 + l15];
        }
        pl += __shfl_xor(pl, 1); pl += __shfl_xor(pl, 2);
        pl += __shfl_xor(pl, 4); pl += __shfl_xor(pl, 8);
        pr += __shfl_xor(pr, 1); pr += __shfl_xor(pr, 2);
        pr += __shfl_xor(pr, 4); pr += __shfl_xor(pr, 8);
        if (l15 == 0) {
          int grow = m0 + lrow + r2;
          if (grow < M) {
            elr[(size_t)grow * 8 + head] = pl;
            elr[(size_t)grow * 8 + 4 + head] = pr;
          }
        }
      }
    }
  }

#pragma unroll
  for (int ri = 0; ri < 4; ++ri) {
    int row = m0 + wr + ri * 16 + quad * 4;
#pragma unroll
    for (int ci = 0; ci < 4; ++ci) {
      int col = n0 + wc + ci * 16 + l15;
      float bv = (MODE == 2) ? bias[col] : 0.f;
#pragma unroll
      for (int r2 = 0; r2 < 4; ++r2) {
        if (row + r2 < M) {
          float v = acc[ri][ci][r2];
          if (MODE == 2) { v += bv; v = fmaxf(v, 0.f); }
          if (MODE == 1)
            ((float*)Cout)[(size_t)(row + r2) * Nc + col] = v;
          else
            Cp[(size_t)(row + r2) * Nc + col + cz] = f2b(v);
        }
      }
    }
  }
}

// ---------------- fused GCN+GAT aggregation (one layer, one launch) ----------------
// mf: [N][512] (gcn features cols 0-255, gat features cols 256-511)
__global__ void agg_both_k(const unsigned short* __restrict__ mf,
                           const int* __restrict__ row_ptr, const int* __restrict__ csr_src,
                           const float* __restrict__ ns, const float* __restrict__ nd,
                           const float* __restrict__ elr,
                           const float* __restrict__ gcn_b, const float* __restrict__ bng_g,
                           const float* __restrict__ bnb_g,
                           const float* __restrict__ gat_b, const float* __restrict__ bng_a,
                           const float* __restrict__ bnb_a,
                           const unsigned short* __restrict__ resid_g,
                           const unsigned short* __restrict__ resid_a,
                           unsigned short* __restrict__ out_g, int ldo_g,
                           unsigned short* __restrict__ out_a, int ldo_a) {
  int node = blockIdx.x * 4 + (threadIdx.x >> 6);
  if (node >= NN) return;
  int lane = threadIdx.x & 63;
  int s = row_ptr[node], e = row_ptr[node + 1];
  // ---- GAT softmax stats ----
  float4 er = *(const float4*)(elr + (size_t)node * 8 + 4);
  float m0 = -1e30f, m1 = -1e30f, m2 = -1e30f, m3 = -1e30f;
  for (int i = s + lane; i < e; i += 64) {
    int u = csr_src[i];
    float4 el = *(const float4*)(elr + (size_t)u * 8);
    float t;
    t = el.x + er.x; t = t > 0.f ? t : 0.2f * t; m0 = fmaxf(m0, t);
    t = el.y + er.y; t = t > 0.f ? t : 0.2f * t; m1 = fmaxf(m1, t);
    t = el.z + er.z; t = t > 0.f ? t : 0.2f * t; m2 = fmaxf(m2, t);
    t = el.w + er.w; t = t > 0.f ? t : 0.2f * t; m3 = fmaxf(m3, t);
  }
#pragma unroll
  for (int off = 1; off < 64; off <<= 1) {
    m0 = fmaxf(m0, __shfl_xor(m0, off));
    m1 = fmaxf(m1, __shfl_xor(m1, off));
    m2 = fmaxf(m2, __shfl_xor(m2, off));
    m3 = fmaxf(m3, __shfl_xor(m3, off));
  }
  float s0 = 0, s1 = 0, s2 = 0, s3 = 0;
  for (int i = s + lane; i < e; i += 64) {
    int u = csr_src[i];
    float4 el = *(const float4*)(elr + (size_t)u * 8);
    float t;
    t = el.x + er.x; t = t > 0.f ? t : 0.2f * t; s0 += expf(t - m0);
    t = el.y + er.y; t = t > 0.f ? t : 0.2f * t; s1 += expf(t - m1);
    t = el.z + er.z; t = t > 0.f ? t : 0.2f * t; s2 += expf(t - m2);
    t = el.w + er.w; t = t > 0.f ? t : 0.2f * t; s3 += expf(t - m3);
  }
#pragma unroll
  for (int off = 1; off < 64; off <<= 1) {
    s0 += __shfl_xor(s0, off);
    s1 += __shfl_xor(s1, off);
    s2 += __shfl_xor(s2, off);
    s3 += __shfl_xor(s3, off);
  }
  int head = lane >> 4;
  float erh = head == 0 ? er.x : head == 1 ? er.y : head == 2 ? er.z : er.w;
  float mh = head == 0 ? m0 : head == 1 ? m1 : head == 2 ? m2 : m3;
  float sh = head == 0 ? s0 : head == 1 ? s1 : head == 2 ? s2 : s3;
  float inv_sh = (sh > 0.f) ? 1.f / sh : 0.f;
  // ---- batched dual gather (16 edges/batch; both GCN and GAT halves) ----
  int eidx = lane & 15;
  float g0 = 0, g1 = 0, g2 = 0, g3 = 0;
  float a0 = 0, a1 = 0, a2 = 0, a3 = 0;
  for (int i0 = s; i0 < e; i0 += 16) {
    int n16 = e - i0; if (n16 > 16) n16 = 16;
    int u_mine = 0; float wg_mine = 0.f, wa_mine = 0.f;
    if (eidx < n16) {
      u_mine = csr_src[i0 + eidx];
      wg_mine = ns[u_mine];
      float t = elr[(size_t)u_mine * 8 + head] + erh;
      t = t > 0.f ? t : 0.2f * t;
      wa_mine = expf(t - mh) * inv_sh;
    }
    for (int e2 = 0; e2 < n16; ++e2) {
      int sl = (lane & 48) | e2;
      int u = __shfl(u_mine, sl);
      float wgv = __shfl(wg_mine, sl);
      float wav = __shfl(wa_mine, sl);
      ushort4 vg = *(const ushort4*)(mf + (size_t)u * 512 + lane * 4);
      ushort4 va = *(const ushort4*)(mf + (size_t)u * 512 + 256 + lane * 4);
      g0 += wgv * b2f(vg.x); g1 += wgv * b2f(vg.y); g2 += wgv * b2f(vg.z); g3 += wgv * b2f(vg.w);
      a0 += wav * b2f(va.x); a1 += wav * b2f(va.y); a2 += wav * b2f(va.z); a3 += wav * b2f(va.w);
    }
  }
  // ---- epilogues ----
  float ndv = nd[node];
  int col = lane * 4;
  float gvals[4] = {g0, g1, g2, g3};
  float avals[4] = {a0, a1, a2, a3};
  ushort4 og, oa;
#pragma unroll
  for (int c = 0; c < 4; ++c) {
    float v = gvals[c] * ndv + gcn_b[col + c];
    v = bng_g[col + c] * v * BNS + bnb_g[col + c];
    v = fmaxf(v, 0.f);
    if (resid_g) v += b2f(resid_g[(size_t)node * 256 + col + c]);
    ((unsigned short*)&og)[c] = f2b(v);
    float v2 = avals[c] + gat_b[col + c];
    v2 = bng_a[col + c] * v2 * BNS + bnb_a[col + c];
    v2 = (v2 > 0.f) ? v2 : (expf(v2) - 1.f);
    if (resid_a) v2 += b2f(resid_a[(size_t)node * 256 + col + c]);
    ((unsigned short*)&oa)[c] = f2b(v2);
  }
  *(ushort4*)(out_g + (size_t)node * ldo_g + col) = og;
  *(ushort4*)(out_a + (size_t)node * ldo_a + col) = oa;
}

// ---------------- per-graph node softmax ----------------
__global__ void gsoftmax_k(const float* __restrict__ att, const int* __restrict__ start,
                           float* __restrict__ alpha) {
  int g = blockIdx.x;
  int s = start[g], e = start[g + 1];
  int tid = threadIdx.x;
  __shared__ float red[256];
  __shared__ float mh[4], sh[4];
  float lm[4] = {-1e30f, -1e30f, -1e30f, -1e30f};
  for (int i = s + tid; i < e; i += 256) {
    float4 a = *(const float4*)(att + (size_t)i * 4);
    lm[0] = fmaxf(lm[0], a.x); lm[1] = fmaxf(lm[1], a.y);
    lm[2] = fmaxf(lm[2], a.z); lm[3] = fmaxf(lm[3], a.w);
  }
#pragma unroll
  for (int h = 0; h < 4; ++h) {
    red[tid] = lm[h]; __syncthreads();
    for (int off = 128; off > 0; off >>= 1) {
      if (tid < off) red[tid] = fmaxf(red[tid], red[tid + off]);
      __syncthreads();
    }
    if (tid == 0) mh[h] = red[0];
    __syncthreads();
  }
  float ls[4] = {0, 0, 0, 0};
  for (int i = s + tid; i < e; i += 256) {
    float4 a = *(const float4*)(att + (size_t)i * 4);
    ls[0] += expf(a.x - mh[0]); ls[1] += expf(a.y - mh[1]);
    ls[2] += expf(a.z - mh[2]); ls[3] += expf(a.w - mh[3]);
  }
#pragma unroll
  for (int h = 0; h < 4; ++h) {
    red[tid] = ls[h]; __syncthreads();
    for (int off = 128; off > 0; off >>= 1) {
      if (tid < off) red[tid] += red[tid + off];
      __syncthreads();
    }
    if (tid == 0) sh[h] = red[0];
    __syncthreads();
  }
  for (int i = s + tid; i < e; i += 256) {
    float4 a = *(const float4*)(att + (size_t)i * 4);
    float4 o;
    o.x = expf(a.x - mh[0]) / sh[0];
    o.y = expf(a.y - mh[1]) / sh[1];
    o.z = expf(a.z - mh[2]) / sh[2];
    o.w = expf(a.w - mh[3]) / sh[3];
    *(float4*)(alpha + (size_t)i * 4) = o;
  }
}

// ---------------- LayerNorms (all bf16 in/out) ----------------
__global__ void ln1_k(const unsigned short* __restrict__ mo, const unsigned short* __restrict__ x,
                      const float* __restrict__ g, const float* __restrict__ b,
                      unsigned short* __restrict__ x1) {
  int node = blockIdx.x * 4 + (threadIdx.x >> 6);
  if (node >= NN) return;
  int lane = threadIdx.x & 63;
  int c = lane * 4;
  ushort4 a = *(const ushort4*)(mo + (size_t)node * HIDDEN + c);
  ushort4 xx = *(const ushort4*)(x + (size_t)node * HIDDEN + c);
  float v0 = b2f(a.x) + b2f(xx.x), v1 = b2f(a.y) + b2f(xx.y);
  float v2 = b2f(a.z) + b2f(xx.z), v3 = b2f(a.w) + b2f(xx.w);
  float sm = v0 + v1 + v2 + v3;
#pragma unroll
  for (int off = 1; off < 64; off <<= 1) sm += __shfl_xor(sm, off);
  float mu = sm * (1.f / 256.f);
  float d0 = v0 - mu, d1 = v1 - mu, d2 = v2 - mu, d3 = v3 - mu;
  float sq = d0 * d0 + d1 * d1 + d2 * d2 + d3 * d3;
#pragma unroll
  for (int off = 1; off < 64; off <<= 1) sq += __shfl_xor(sq, off);
  float inv = rsqrtf(sq * (1.f / 256.f) + LN_EPS);
  ushort4 ob;
  ob.x = f2b(g[c + 0] * d0 * inv + b[c + 0]);
  ob.y = f2b(g[c + 1] * d1 * inv + b[c + 1]);
  ob.z = f2b(g[c + 2] * d2 * inv + b[c + 2]);
  ob.w = f2b(g[c + 3] * d3 * inv + b[c + 3]);
  *(ushort4*)(x1 + (size_t)node * HIDDEN + c) = ob;
}

__global__ void ln2_k(const unsigned short* __restrict__ ff2o, const float* __restrict__ ffb2,
                      const unsigned short* __restrict__ x1,
                      const float* __restrict__ g, const float* __restrict__ b,
                      unsigned short* __restrict__ x2) {
  int node = blockIdx.x * 4 + (threadIdx.x >> 6);
  if (node >= NN) return;
  int lane = threadIdx.x & 63;
  int c = lane * 4;
  ushort4 a = *(const ushort4*)(ff2o + (size_t)node * HIDDEN + c);
  ushort4 xx = *(const ushort4*)(x1 + (size_t)node * HIDDEN + c);
  float v0 = b2f(a.x) + ffb2[c + 0] + b2f(xx.x), v1 = b2f(a.y) + ffb2[c + 1] + b2f(xx.y);
  float v2 = b2f(a.z) + ffb2[c + 2] + b2f(xx.z), v3 = b2f(a.w) + ffb2[c + 3] + b2f(xx.w);
  float sm = v0 + v1 + v2 + v3;
#pragma unroll
  for (int off = 1; off < 64; off <<= 1) sm += __shfl_xor(sm, off);
  float mu = sm * (1.f / 256.f);
  float d0 = v0 - mu, d1 = v1 - mu, d2 = v2 - mu, d3 = v3 - mu;
  float sq = d0 * d0 + d1 * d1 + d2 * d2 + d3 * d3;
#pragma unroll
  for (int off = 1; off < 64; off <<= 1) sq += __shfl_xor(sq, off);
  float inv = rsqrtf(sq * (1.f / 256.f) + LN_EPS);
  ushort4 ob;
  ob.x = f2b(g[c + 0] * d0 * inv + b[c + 0]);
  ob.y = f2b(g[c + 1] * d1 * inv + b[c + 1]);
  ob.z = f2b(g[c + 2] * d2 * inv + b[c + 2]);
  ob.w = f2b(g[c + 3] * d3 * inv + b[c + 3]);
  *(ushort4*)(x2 + (size_t)node * HIDDEN + c) = ob;
}

// ---------------- readout (output 0) ----------------
__global__ void readout_k(const unsigned short* __restrict__ x2, const int* __restrict__ start,
                          float* __restrict__ out0) {
  int g = blockIdx.x;
  int c = threadIdx.x;
  float acc = 0.f;
  for (int i = start[g]; i < start[g + 1]; ++i) acc += b2f(x2[(size_t)i * HIDDEN + c]);
  out0[(size_t)g * HIDDEN + c] = acc;
}

// ---------------- workspace layout (bytes) ----------------
static const size_t OFF_BUFA   = 0;
static const size_t OFF_C01    = 128000000;
static const size_t OFF_HG0    = 179200000;
static const size_t OFF_HA0    = 204800000;
static const size_t OFF_MF     = 230400000;   // [N][512] interleaved m1|f1 (51.2 MB)
static const size_t OFF_XCAT   = 281600000;
static const size_t OFF_XB     = 358400000;
static const size_t OFF_MO     = 384000000;
static const size_t OFF_X1     = 409600000;
static const size_t OFF_ATT    = 435200000;
static const size_t OFF_ALPHA  = OFF_ATT + 800000;
static const size_t OFF_ELR0   = OFF_ALPHA + 800000;
static const size_t OFF_ELR1   = OFF_ELR0 + 1600000;
static const size_t OFF_START  = OFF_ELR1 + 1600000;
static const size_t OFF_DEGO   = OFF_START + 1024;
static const size_t OFF_DEGI   = OFF_DEGO + 200704;
static const size_t OFF_FILL   = OFF_DEGI + 200704;
static const size_t OFF_NS     = OFF_FILL + 200704;
static const size_t OFF_ND     = OFF_NS + 200704;
static const size_t OFF_ROWP   = OFF_ND + 200704;
static const size_t OFF_BSUM   = OFF_ROWP + 200704;
static const size_t OFF_BOFF   = OFF_BSUM + 1024;
static const size_t OFF_CSRS   = OFF_BOFF + 1024;
static const size_t OFF_W01T   = OFF_CSRS + 3200000;
static const size_t OFF_W1T    = OFF_W01T + 1310720;
static const size_t OFF_W1GT   = OFF_W1T + 131072;
static const size_t OFF_GATEWT = OFF_W1GT + 131072;
static const size_t OFF_WMVT   = OFF_GATEWT + 262144;
static const size_t OFF_CTWT   = OFF_WMVT + 1048576;
static const size_t OFF_FFW1T  = OFF_CTWT + 524288;
static const size_t OFF_FFW2T  = OFF_FFW1T + 262144;
static const size_t WS_NEED    = OFF_FFW2T + 262144;

extern "C" void kernel_launch(void* const* d_in, const int* in_sizes, int n_in,
                              void* d_out, int out_size, void* d_ws, size_t ws_size,
                              hipStream_t stream) {
  if (ws_size < WS_NEED) return;

  const float* h       = (const float*)d_in[0];
  const float* gcn_w0  = (const float*)d_in[1];
  const float* gcn_b0  = (const float*)d_in[2];
  const float* gcn_w1  = (const float*)d_in[3];
  const float* gcn_b1  = (const float*)d_in[4];
  const float* bn_gcn0_g = (const float*)d_in[5];
  const float* bn_gcn0_b = (const float*)d_in[6];
  const float* bn_gcn1_g = (const float*)d_in[7];
  const float* bn_gcn1_b = (const float*)d_in[8];
  const float* gat_w0  = (const float*)d_in[9];
  const float* gat_al0 = (const float*)d_in[10];
  const float* gat_ar0 = (const float*)d_in[11];
  const float* gat_bias0 = (const float*)d_in[12];
  const float* gat_w1  = (const float*)d_in[13];
  const float* gat_al1 = (const float*)d_in[14];
  const float* gat_ar1 = (const float*)d_in[15];
  const float* gat_bias1 = (const float*)d_in[16];
  const float* bn_gat0_g = (const float*)d_in[17];
  const float* bn_gat0_b = (const float*)d_in[18];
  const float* bn_gat1_g = (const float*)d_in[19];
  const float* bn_gat1_b = (const float*)d_in[20];
  const float* gate_w  = (const float*)d_in[21];
  const float* gate_b  = (const float*)d_in[22];
  const float* qw      = (const float*)d_in[23];
  const float* kw      = (const float*)d_in[24];
  const float* vw      = (const float*)d_in[25];
  const float* ct_w    = (const float*)d_in[26];
  const float* ff_w1   = (const float*)d_in[27];
  const float* ff_b1   = (const float*)d_in[28];
  const float* ff_w2   = (const float*)d_in[29];
  const float* ff_b2   = (const float*)d_in[30];
  const float* ln_g    = (const float*)d_in[31];
  const float* ln_b    = (const float*)d_in[32];
  const int* srcv = (const int*)d_in[33];
  const int* dstv = (const int*)d_in[34];
  const int* gid  = (const int*)d_in[35];

  char* ws = (char*)d_ws;
  unsigned short* h_bf = (unsigned short*)(ws + OFF_BUFA);
  unsigned short* ff1o = (unsigned short*)(ws + OFF_BUFA);
  unsigned short* ff2o = (unsigned short*)(ws + OFF_BUFA + 51200000);
  unsigned short* x2   = (unsigned short*)(ws + OFF_BUFA + 76800000);
  unsigned short* c01  = (unsigned short*)(ws + OFF_C01);
  unsigned short* hg0  = (unsigned short*)(ws + OFF_HG0);
  unsigned short* ha0  = (unsigned short*)(ws + OFF_HA0);
  unsigned short* mf   = (unsigned short*)(ws + OFF_MF);
  unsigned short* xcat = (unsigned short*)(ws + OFF_XCAT);
  unsigned short* xb   = (unsigned short*)(ws + OFF_XB);
  unsigned short* mo   = (unsigned short*)(ws + OFF_MO);
  unsigned short* x1   = (unsigned short*)(ws + OFF_X1);
  float* att           = (float*)(ws + OFF_ATT);
  float* alpha         = (float*)(ws + OFF_ALPHA);
  float* elr0          = (float*)(ws + OFF_ELR0);
  float* elr1          = (float*)(ws + OFF_ELR1);
  int* start   = (int*)(ws + OFF_START);
  int* deg_out = (int*)(ws + OFF_DEGO);
  int* deg_in  = (int*)(ws + OFF_DEGI);
  int* fill    = (int*)(ws + OFF_FILL);
  float* ns    = (float*)(ws + OFF_NS);
  float* nd    = (float*)(ws + OFF_ND);
  int* row_ptr = (int*)(ws + OFF_ROWP);
  int* bsum    = (int*)(ws + OFF_BSUM);
  int* boff    = (int*)(ws + OFF_BOFF);
  int* csr_src = (int*)(ws + OFF_CSRS);
  unsigned short* w01t   = (unsigned short*)(ws + OFF_W01T);
  unsigned short* w1t    = (unsigned short*)(ws + OFF_W1T);
  unsigned short* w1gt   = (unsigned short*)(ws + OFF_W1GT);
  unsigned short* gatewt = (unsigned short*)(ws + OFF_GATEWT);
  unsigned short* wmvt   = (unsigned short*)(ws + OFF_WMVT);
  unsigned short* w2t    = (unsigned short*)(ws + OFF_CTWT);
  unsigned short* ffw1t  = (unsigned short*)(ws + OFF_FFW1T);
  unsigned short* ffw2t  = (unsigned short*)(ws + OFF_FFW2T);

  float* out0 = (float*)d_out;            // readout [128,256]
  float* out1 = out0 + NG * HIDDEN;       // init_avg_h [128,1280]

  hipMemsetAsync(deg_out, 0, 3 * 200704, stream);   // deg_out + deg_in + fill (contiguous)
  hipMemsetAsync(out1, 0, NG * DIN * 4, stream);
  hipMemsetAsync(att, 0, NN * 4 * 4, stream);

  // merged weight prep (1 dispatch)
  prep_all_k<<<6656, 256, 0, stream>>>(gcn_w0, gat_w0, gcn_w1, gat_w1, gate_w, ff_w1, ff_w2,
                                       qw, kw, vw, ct_w,
                                       w01t, w1t, w1gt, gatewt, ffw1t, ffw2t, wmvt, w2t);

  // graph structure (merged)
  bounds_deg_k<<<(NE + 255) / 256, 256, 0, stream>>>(gid, start, srcv, dstv, deg_out, deg_in);
  const int NB_SCAN = (NN + 255) / 256;
  scan_local_k<<<NB_SCAN, 256, 0, stream>>>(deg_in, deg_out, row_ptr, bsum, ns, nd);
  scan_bsum_k<<<1, 256, 0, stream>>>(bsum, boff, NB_SCAN, row_ptr);
  scan_add_k<<<NB_SCAN, 256, 0, stream>>>(row_ptr, boff);
  fill_csr_k<<<(NE + 255) / 256, 256, 0, stream>>>(srcv, dstv, row_ptr, fill, csr_src, NE);

  // fused h->bf16 + per-graph sums, then divide
  cvt_avg_k<<<NN / 50, 320, 0, stream>>>(h, gid, h_bf, out1);
  div_avg_k<<<(NG * DIN + 255) / 256, 256, 0, stream>>>(start, out1);

  const int MB = (NN + 127) / 128;
  // GEMM1: h @ [gcn_w0 | gat_w0] -> c01 [N,512] with fused elr0 (gat cols >=256)
  gemm_bf16<8><<<dim3(4, MB), 256, 0, stream>>>(h_bf, w01t, c01, nullptr, NN, 1280, 512,
                                                nullptr, nullptr, nullptr,
                                                gat_al0, gat_ar0, elr0, 256);
  // layer 0 fused aggregation
  agg_both_k<<<NN / 4, 256, 0, stream>>>(c01, row_ptr, csr_src, ns, nd, elr0,
                                         gcn_b0, bn_gcn0_g, bn_gcn0_b,
                                         gat_bias0, bn_gat0_g, bn_gat0_b,
                                         nullptr, nullptr, hg0, 256, ha0, 256);
  // layer 1: merged GEMMs write interleaved mf [N][512]; z=1 fused elr1
  gemm_bf16<8><<<dim3(2, MB, 2), 256, 0, stream>>>(hg0, w1t, mf, nullptr, NN, 256, 512,
                                                   nullptr, nullptr, nullptr,
                                                   gat_al1, gat_ar1, elr1, 0);
  // layer 1 fused aggregation (+residuals) -> xcat halves
  agg_both_k<<<NN / 4, 256, 0, stream>>>(mf, row_ptr, csr_src, ns, nd, elr1,
                                         gcn_b1, bn_gcn1_g, bn_gcn1_b,
                                         gat_bias1, bn_gat1_g, bn_gat1_b,
                                         hg0, ha0, xcat, 512, xcat + 256, 512);
  // gate GEMM with fused sigmoid-blend epilogue -> xb
  gemm_bf16<7><<<dim3(2, MB), 256, 0, stream>>>(xcat, gatewt, xb, gate_b, NN, 512, 256,
                                                xcat, nullptr, nullptr,
                                                nullptr, nullptr, nullptr, 0);
  // transformer: att = x^T M_h x via att epilogue (M-part only; V folded into W2)
  gemm_bf16<4><<<dim3(8, MB), 256, 0, stream>>>(xb, wmvt, nullptr, nullptr, NN, 256, 1024,
                                                xb, att, nullptr,
                                                nullptr, nullptr, nullptr, 0);
  gsoftmax_k<<<NG, 256, 0, stream>>>(att, start, alpha);
  // mo = (alpha-scaled xb, head-major K=1024) @ W2cat
  gemm_bf16<6><<<dim3(2, MB), 256, 0, stream>>>(xb, w2t, mo, nullptr, NN, 1024, 256,
                                                nullptr, nullptr, alpha,
                                                nullptr, nullptr, nullptr, 0);
  ln1_k<<<NN / 4, 256, 0, stream>>>(mo, xb, ln_g, ln_b, x1);
  gemm_bf16<2><<<dim3(4, MB), 256, 0, stream>>>(x1, ffw1t, ff1o, ff_b1, NN, 256, 512,
                                                nullptr, nullptr, nullptr,
                                                nullptr, nullptr, nullptr, 0);
  gemm_bf16<0><<<dim3(2, MB), 256, 0, stream>>>(ff1o, ffw2t, ff2o, nullptr, NN, 512, 256,
                                                nullptr, nullptr, nullptr,
                                                nullptr, nullptr, nullptr, 0);
  ln2_k<<<NN / 4, 256, 0, stream>>>(ff2o, ff_b2, x1, ln_g, ln_b, x2);
  readout_k<<<NG, 256, 0, stream>>>(x2, start, out0);
}